// Round 7
// baseline (763.802 us; speedup 1.0000x reference)
//
#include <hip/hip_runtime.h>
#include <hip/hip_bf16.h>

#define NCRYST 256
#define AATOMS 64
#define KNBR   20
#define HID    128
#define LAT    256
#define NRBF   128
#define NBLK   3
#define NATOMS (NCRYST * AATOMS)   // 16384
#define NEDGE  (NATOMS * KNBR)     // 327680
#define NPART  2                   // agg partial slices per crystal
#define DQ     4096                // dist-table knots over [0, CUT]
#define PI_F   3.14159265358979323846f
#define CUT_F  6.0f
#define CHB    1040                // LDS A chunk stride: 1024 B payload + 16 B pad

typedef short short8 __attribute__((ext_vector_type(8)));   // 8 bf16 (4 VGPRs)
typedef float f32x4  __attribute__((ext_vector_type(4)));   // MFMA C/D

__device__ __forceinline__ float bf2f(__hip_bfloat16 x) { return __bfloat162float(x); }
__device__ __forceinline__ __hip_bfloat16 f2bf(float x) { return __float2bfloat16(x); }
__device__ __forceinline__ float s2f(short x) {
  return __uint_as_float(((unsigned)(unsigned short)x) << 16);
}
__device__ __forceinline__ short f2s(float x) {
  union { short s; __hip_bfloat16 b; } u; u.b = f2bf(x); return u.s;
}

#define DMA16(gptr, lptr) __builtin_amdgcn_global_load_lds( \
    (const __attribute__((address_space(1))) void*)(gptr),  \
    (__attribute__((address_space(3))) void*)(lptr), 16, 0, 0)

// s_waitcnt immediates: vm = bits[3:0] (+[15:14]), exp = bits[6:4] (7 = no wait),
// lgkm = bits[11:8] (0xF = no wait).
#define WCNT_VM9_LGKM0  0x0079
#define WCNT_VM8_LGKM0  0x0078
#define WCNT_VM4_LGKM0  0x0074
#define WCNT_VM0_LGKM0  0x0070
#define WCNT_LGKM0_ONLY 0xC07F   // vmcnt=63 (no wait), lgkmcnt(0)

// ---------------------------------------------------------------- cart coords
__global__ void k_cart(const float* __restrict__ frac, const float* __restrict__ lengths,
                       const float* __restrict__ angles, float* __restrict__ cart) {
  int atom = blockIdx.x * blockDim.x + threadIdx.x;
  if (atom >= NATOMS) return;
  int c = atom >> 6;
  float al = angles[c*3+0] * (PI_F/180.f);
  float be = angles[c*3+1] * (PI_F/180.f);
  float ga = angles[c*3+2] * (PI_F/180.f);
  float ca = cosf(al), cb = cosf(be), cg = cosf(ga), sg = sinf(ga);
  float a = lengths[c*3+0], b = lengths[c*3+1], cl = lengths[c*3+2];
  float cx = cl * cb;
  float cy = cl * (ca - cb*cg) / sg;
  float cz = sqrtf(fmaxf(cl*cl - cx*cx - cy*cy, 1e-8f));
  float f0 = frac[atom*3+0], f1 = frac[atom*3+1], f2 = frac[atom*3+2];
  cart[atom*3+0] = f0*a + f1*(b*cg) + f2*cx;
  cart[atom*3+1] = f1*(b*sg) + f2*cy;
  cart[atom*3+2] = f2*cz;
}

// ---------------- edge geometry: unit + dist; also init fbuf[e] = b_force
__global__ void k_edge(const float* __restrict__ cart, const int* __restrict__ src,
                       const int* __restrict__ dst, float* __restrict__ unit,
                       float* __restrict__ dist, const float* __restrict__ b_force,
                       float* __restrict__ fbuf) {
  int e = blockIdx.x * blockDim.x + threadIdx.x;
  if (e >= NEDGE) return;
  int s = src[e], d = dst[e];
  float dx = cart[d*3+0] - cart[s*3+0];
  float dy = cart[d*3+1] - cart[s*3+1];
  float dz = cart[d*3+2] - cart[s*3+2];
  float dd = sqrtf(dx*dx + dy*dy + dz*dz + 1e-12f);
  float inv = 1.f / dd;
  dist[e] = dd;
  unit[e*3+0] = dx*inv; unit[e*3+1] = dy*inv; unit[e*3+2] = dz*inv;
  fbuf[e] = b_force[0];
}

// ---------------- dist tables: T[0]=rbf@W_edge[256:384], T[1+i]=rbf@Wb_rbf[i]
__global__ __launch_bounds__(128) void k_tab(const float* __restrict__ W_edge,
                                             const float* __restrict__ Wb_rbf,
                                             float* __restrict__ T) {
  int q = blockIdx.x, n = threadIdx.x;
  __shared__ float rv[128];
  float d = (float)q * (CUT_F / (float)(DQ - 1));
  float env = 0.5f * (cosf(PI_F * fminf(d * (1.f/CUT_F), 1.f)) + 1.f);
  float t = (d - (float)n * (CUT_F/(NRBF-1))) * ((NRBF-1)/CUT_F);
  rv[n] = expf(-t*t) * env;
  __syncthreads();
  float a0 = 0.f, a1 = 0.f, a2 = 0.f, a3 = 0.f;
  for (int j = 0; j < 128; ++j) {
    float r = rv[j];
    a0 = fmaf(r, W_edge[(256 + j)*128 + n], a0);
    a1 = fmaf(r, Wb_rbf[0*16384 + j*128 + n], a1);
    a2 = fmaf(r, Wb_rbf[1*16384 + j*128 + n], a2);
    a3 = fmaf(r, Wb_rbf[2*16384 + j*128 + n], a3);
  }
  T[(0*DQ + q)*128 + n] = a0;
  T[(1*DQ + q)*128 + n] = a1;
  T[(2*DQ + q)*128 + n] = a2;
  T[(3*DQ + q)*128 + n] = a3;
}

// ----------------- weights -> bf16 n-major K=128 blocks (W_in stays K=384)
__global__ void k_wcast(const float* __restrict__ W_in, const float* __restrict__ W_edge,
                        const float* __restrict__ Wb_upd, const float* __restrict__ Wb_msg,
                        const float* __restrict__ Wb_atom, const float* __restrict__ W_fc1,
                        const float* __restrict__ W_fc2, __hip_bfloat16* __restrict__ WT) {
  int idx = blockIdx.x * 256 + threadIdx.x;
  if (idx >= 360448) return;
  if (idx < 49152) {
    int n = idx / 384, k = idx % 384;
    WT[idx] = f2bf(W_in[k*128 + n]);
    return;
  }
  int t = idx - 49152;
  int b = t >> 14, q = t & 16383;
  int n = q >> 7, k = q & 127;
  const float* S; int krow;
  if (b == 0)       { S = W_edge; krow = k; }
  else if (b == 1)  { S = W_edge; krow = 128 + k; }
  else if (b <= 10) { int i = (b-2)/3, part = (b-2)%3;
                      S = Wb_upd + i*49152; krow = part*128 + k; }
  else if (b <= 13) { S = Wb_msg + (b-11)*16384; krow = k; }
  else if (b <= 16) { S = Wb_atom + (b-14)*16384; krow = k; }
  else if (b == 17) { S = W_fc1; krow = k; }
  else              { S = W_fc2; krow = k; }
  WT[idx] = f2bf(S[krow*128 + n]);
}

// ============ MFMA h: h = relu([emb[atype]|z]@W_in + b), 64 rows/block
__global__ __launch_bounds__(256) void k_hm(
    const int* __restrict__ atype, const float* __restrict__ z,
    const float* __restrict__ emb, const __hip_bfloat16* __restrict__ WTin,
    const float* __restrict__ b, float* __restrict__ h,
    __hip_bfloat16* __restrict__ h_bf) {
  const int tid = threadIdx.x;
  const int w = tid >> 6, lane = tid & 63, ln = lane & 15, qd = lane >> 4;
  const int row0w = blockIdx.x * 64 + w * 16;
  const int arow = row0w + ln;
  const float* esrc = emb + (size_t)atype[arow] * 128;
  const float* zsrc = z + (size_t)(arow >> 6) * LAT;

  short8 af[12];
#pragma unroll
  for (int ks = 0; ks < 4; ++ks) {
    float4 v0 = *(const float4*)(esrc + ks*32 + qd*8);
    float4 v1 = *(const float4*)(esrc + ks*32 + qd*8 + 4);
    af[ks] = (short8){f2s(v0.x),f2s(v0.y),f2s(v0.z),f2s(v0.w),
                      f2s(v1.x),f2s(v1.y),f2s(v1.z),f2s(v1.w)};
  }
#pragma unroll
  for (int ks = 4; ks < 12; ++ks) {
    float4 v0 = *(const float4*)(zsrc + (ks-4)*32 + qd*8);
    float4 v1 = *(const float4*)(zsrc + (ks-4)*32 + qd*8 + 4);
    af[ks] = (short8){f2s(v0.x),f2s(v0.y),f2s(v0.z),f2s(v0.w),
                      f2s(v1.x),f2s(v1.y),f2s(v1.z),f2s(v1.w)};
  }

  const short* Wb = (const short*)WTin + ln*384 + qd*8;
  f32x4 acc[8];
#pragma unroll
  for (int ct = 0; ct < 8; ++ct) acc[ct] = (f32x4){0,0,0,0};
#pragma unroll
  for (int ks = 0; ks < 12; ++ks)
#pragma unroll
    for (int ct = 0; ct < 8; ++ct)
      acc[ct] = __builtin_amdgcn_mfma_f32_16x16x32_bf16(af[ks],
                  *(const short8*)(Wb + ct*16*384 + ks*32), acc[ct], 0,0,0);

#pragma unroll
  for (int ct = 0; ct < 8; ++ct) {
    int col = ct*16 + ln;
    float bias = b[col];
#pragma unroll
    for (int reg = 0; reg < 4; ++reg) {
      int crow = row0w + qd*4 + reg;
      float v = fmaxf(acc[ct][reg] + bias, 0.f);
      size_t o = (size_t)crow*128 + col;
      h[o] = v;
      h_bf[o] = f2bf(v);
    }
  }
}

// ============ dual projection: O1 = A@WT1, O2 = A@WT2 (no bias/relu, bf16)
__global__ __launch_bounds__(256) void k_uv2(
    const __hip_bfloat16* __restrict__ A,
    const __hip_bfloat16* __restrict__ WT1, const __hip_bfloat16* __restrict__ WT2,
    __hip_bfloat16* __restrict__ O1, __hip_bfloat16* __restrict__ O2) {
  const int tid = threadIdx.x;
  const int w = tid >> 6, lane = tid & 63, ln = lane & 15, qd = lane >> 4;
  const int row0w = blockIdx.x * 64 + w * 16;
  const int arow = row0w + ln;

  short8 af[4];
  const short* pa = (const short*)A + (size_t)arow*128 + qd*8;
#pragma unroll
  for (int ks = 0; ks < 4; ++ks) af[ks] = *(const short8*)(pa + ks*32);

  f32x4 a1[8], a2[8];
#pragma unroll
  for (int ct = 0; ct < 8; ++ct) { a1[ct] = (f32x4){0,0,0,0}; a2[ct] = (f32x4){0,0,0,0}; }
#pragma unroll
  for (int ct = 0; ct < 8; ++ct) {
    const short* b1 = (const short*)WT1 + (ct*16 + ln)*128 + qd*8;
    const short* b2 = (const short*)WT2 + (ct*16 + ln)*128 + qd*8;
#pragma unroll
    for (int ks = 0; ks < 4; ++ks) {
      a1[ct] = __builtin_amdgcn_mfma_f32_16x16x32_bf16(af[ks], *(const short8*)(b1 + ks*32), a1[ct], 0,0,0);
      a2[ct] = __builtin_amdgcn_mfma_f32_16x16x32_bf16(af[ks], *(const short8*)(b2 + ks*32), a2[ct], 0,0,0);
    }
  }
#pragma unroll
  for (int ct = 0; ct < 8; ++ct) {
    int col = ct*16 + ln;
#pragma unroll
    for (int reg = 0; reg < 4; ++reg) {
      size_t o = (size_t)(row0w + qd*4 + reg)*128 + col;
      O1[o] = f2bf(a1[ct][reg]);
      O2[o] = f2bf(a2[ct][reg]);
    }
  }
}

// ============ m init v2: m = relu(u0[src] + v0[dst] + T0(d) + b)
__global__ __launch_bounds__(256) void k_minit(
    const int* __restrict__ src, const int* __restrict__ dst,
    const float* __restrict__ dist,
    const __hip_bfloat16* __restrict__ u0, const __hip_bfloat16* __restrict__ v0,
    const float* __restrict__ T0, const float* __restrict__ b,
    __hip_bfloat16* __restrict__ m) {
  const int t = threadIdx.x;
  const int li = t & 15, ei = t >> 4;
  float bcol[8];
#pragma unroll
  for (int u = 0; u < 8; ++u) bcol[u] = b[li*8 + u];

  int e[4]; float dd[4]; short8 us[4], vs[4];
#pragma unroll
  for (int g = 0; g < 4; ++g) {
    e[g] = blockIdx.x*64 + g*16 + ei;
    dd[g] = dist[e[g]];
    int s = src[e[g]], d = dst[e[g]];
    us[g] = *(const short8*)((const short*)u0 + (size_t)s*128 + li*8);
    vs[g] = *(const short8*)((const short*)v0 + (size_t)d*128 + li*8);
  }
  float t0v[4][8], t1v[4][8]; float fr[4]; bool in[4];
#pragma unroll
  for (int g = 0; g < 4; ++g) {
    in[g] = dd[g] < CUT_F;
    float x = fminf(dd[g], CUT_F) * ((float)(DQ - 1) / CUT_F);
    int i0 = (int)x;
    fr[g] = x - (float)i0;
    const float* tp = T0 + (size_t)i0*128 + li*8;
    *(float4*)&t0v[g][0] = *(const float4*)tp;
    *(float4*)&t0v[g][4] = *(const float4*)(tp + 4);
    *(float4*)&t1v[g][0] = *(const float4*)(tp + 128);
    *(float4*)&t1v[g][4] = *(const float4*)(tp + 132);
  }
#pragma unroll
  for (int g = 0; g < 4; ++g) {
    short8 o;
#pragma unroll
    for (int u = 0; u < 8; ++u) {
      float tv = in[g] ? fmaf(fr[g], t1v[g][u] - t0v[g][u], t0v[g][u]) : 0.f;
      float v = s2f(us[g][u]) + s2f(vs[g][u]) + tv + bcol[u];
      o[u] = f2s(fmaxf(v, 0.f));
    }
    *(uint4*)((short*)m + (size_t)e[g]*128 + li*8) = *(uint4*)&o;
  }
}

// ============ m update v2: block = (crystal, half), 10 tiles of 64 edges.
// uu[src]+vv[dst] gathers via one-hot MFMA; crystal B-frags in regs once/block.
template<int MODE>
__global__ __launch_bounds__(256) void k_eup(
    const int* __restrict__ src, const int* __restrict__ dst,
    __hip_bfloat16* __restrict__ m,
    const __hip_bfloat16* __restrict__ uu, const __hip_bfloat16* __restrict__ vv,
    const __hip_bfloat16* __restrict__ WTmm, const float* __restrict__ b,
    const float* __restrict__ Wf, float* __restrict__ fout) {
  __shared__ short Bs[128 * 132];                     // 33.8 KB
  __shared__ __align__(16) char Abuf[2][17 * CHB];    // 2 x 17.7 KB
  __shared__ short srcS[640], dstS[640];              //  2.5 KB
  const int tid = threadIdx.x;
  const int w = tid >> 6, lane = tid & 63, ln = lane & 15, qd = lane >> 4;
  const int cg = w & 1, rh = w >> 1;
  const int e_loc = lane >> 4;                        // edge within 4-edge chunk
  const int sgc = (lane & 15) ^ (e_loc << 2);         // pre-swizzled source col-group
  const int cry = blockIdx.x >> 1, half = blockIdx.x & 1;
  const int ebase = cry * 1280 + half * 640;
  const int ca = cry * 64;                            // crystal atom base

#pragma unroll
  for (int i = 0; i < 8; ++i) {
    int g = i * 256 + tid;
    int colb = g >> 4, ch = g & 15;
    *(uint4*)&Bs[colb*132 + ch*8] = ((const uint4*)((const short*)WTmm + colb*128))[ch];
  }
  for (int i = tid; i < 640; i += 256) {
    srcS[i] = (short)(src[ebase + i] & 63);
    dstS[i] = (short)(dst[ebase + i] & 63);
  }

  float bias4[4], wf4[4];
#pragma unroll
  for (int ct = 0; ct < 4; ++ct) bias4[ct] = b[cg*64 + ct*16 + ln];
  if constexpr (MODE == 2) {
#pragma unroll
    for (int ct = 0; ct < 4; ++ct) wf4[ct] = Wf[cg*64 + ct*16 + ln];
  }

  // ---- crystal uu/vv gather B-fragments: B[k=atom][col], regs, once/block ----
  short8 Bu[2][4], Bv[2][4];
#pragma unroll
  for (int ks = 0; ks < 2; ++ks)
#pragma unroll
    for (int ct = 0; ct < 4; ++ct) {
      const int col = cg*64 + ct*16 + ln;
#pragma unroll
      for (int j = 0; j < 8; ++j) {
        const size_t ro = (size_t)(ca + ks*32 + qd*8 + j) * 128 + col;
        Bu[ks][ct][j] = ((const short*)uu)[ro];
        Bv[ks][ct][j] = ((const short*)vv)[ro];
      }
    }

#pragma unroll
  for (int t4 = 0; t4 < 4; ++t4) {
    int chunk = w * 4 + t4;
    const short* gp = (const short*)m + (size_t)(ebase + chunk*4 + e_loc)*128 + sgc*8;
    DMA16(gp, Abuf[0] + chunk * CHB);
  }

  for (int t = 0; t < 10; ++t) {
    const int nb = t & 1;
    if (t < 9) {
#pragma unroll
      for (int t4 = 0; t4 < 4; ++t4) {
        int chunk = w * 4 + t4;
        const short* gp = (const short*)m +
            (size_t)(ebase + (t+1)*64 + chunk*4 + e_loc)*128 + sgc*8;
        DMA16(gp, Abuf[nb^1] + chunk * CHB);
      }
      __builtin_amdgcn_s_waitcnt(WCNT_VM4_LGKM0);   // keep next tile's 4 DMAs
    } else {
      __builtin_amdgcn_s_waitcnt(WCNT_VM0_LGKM0);
    }
    __builtin_amdgcn_s_barrier();

    const char* Ab = Abuf[nb];
    const int e0 = ebase + t*64;
    const int l0 = t*64;

    const int rowA = rh*32 + ln, rowB = rowA + 16;
    const int sa = srcS[l0 + rowA], da = dstS[l0 + rowA];
    const int sb = srcS[l0 + rowB], db = dstS[l0 + rowB];

    f32x4 acc0[4], acc1[4];
#pragma unroll
    for (int ct = 0; ct < 4; ++ct) { acc0[ct] = (f32x4){0,0,0,0}; acc1[ct] = (f32x4){0,0,0,0}; }
    const int sx = (ln & 3) << 2;                     // rowA&3 == rowB&3 == ln&3
#pragma unroll
    for (int ks = 0; ks < 4; ++ks) {
      int slot = ((ks*4 + qd) ^ sx) << 4;
      short8 aA = *(const short8*)(Ab + (rowA>>2)*CHB + (ln&3)*256 + slot);
      short8 aB = *(const short8*)(Ab + (rowB>>2)*CHB + (ln&3)*256 + slot);
#pragma unroll
      for (int ct = 0; ct < 4; ++ct) {
        short8 bb = *(const short8*)&Bs[(cg*64 + ct*16 + ln)*132 + ks*32 + qd*8];
        acc0[ct] = __builtin_amdgcn_mfma_f32_16x16x32_bf16(aA, bb, acc0[ct], 0,0,0);
        acc1[ct] = __builtin_amdgcn_mfma_f32_16x16x32_bf16(aB, bb, acc1[ct], 0,0,0);
      }
    }

#pragma unroll
    for (int ks = 0; ks < 2; ++ks) {
      short8 ohAu, ohAv, ohBu, ohBv;
#pragma unroll
      for (int j = 0; j < 8; ++j) {
        const int kk = ks*32 + qd*8 + j;
        ohAu[j] = (sa == kk) ? (short)0x3F80 : (short)0;
        ohAv[j] = (da == kk) ? (short)0x3F80 : (short)0;
        ohBu[j] = (sb == kk) ? (short)0x3F80 : (short)0;
        ohBv[j] = (db == kk) ? (short)0x3F80 : (short)0;
      }
#pragma unroll
      for (int ct = 0; ct < 4; ++ct) {
        acc0[ct] = __builtin_amdgcn_mfma_f32_16x16x32_bf16(ohAu, Bu[ks][ct], acc0[ct], 0,0,0);
        acc0[ct] = __builtin_amdgcn_mfma_f32_16x16x32_bf16(ohAv, Bv[ks][ct], acc0[ct], 0,0,0);
        acc1[ct] = __builtin_amdgcn_mfma_f32_16x16x32_bf16(ohBu, Bu[ks][ct], acc1[ct], 0,0,0);
        acc1[ct] = __builtin_amdgcn_mfma_f32_16x16x32_bf16(ohBv, Bv[ks][ct], acc1[ct], 0,0,0);
      }
    }

    float vreg[2][4][4];
#pragma unroll
    for (int mt = 0; mt < 2; ++mt) {
      const f32x4* acc = mt ? acc1 : acc0;
#pragma unroll
      for (int reg = 0; reg < 4; ++reg) {
        int lrow = rh*32 + mt*16 + qd*4 + reg;
        float fp = 0.f;
#pragma unroll
        for (int ct = 0; ct < 4; ++ct) {
          int col = cg*64 + ct*16 + ln;
          int colg = col >> 3;
          float res = s2f(*(const short*)(Ab + (lrow>>2)*CHB + (lrow&3)*256
                         + ((colg ^ ((lrow&3)<<2)) << 4) + (col&7)*2));
          float val = fmaxf(acc[ct][reg] + bias4[ct], 0.f) + res;
          if constexpr (MODE == 1) vreg[mt][reg][ct] = val;
          else fp = fmaf(val, wf4[ct], fp);
        }
        if constexpr (MODE == 2) {
          fp += __shfl_xor(fp, 1, 64);
          fp += __shfl_xor(fp, 2, 64);
          fp += __shfl_xor(fp, 4, 64);
          fp += __shfl_xor(fp, 8, 64);
          if (ln == 0) atomicAdd(&fout[e0 + lrow], fp);
        }
      }
    }

    if constexpr (MODE == 1) {
      __builtin_amdgcn_s_waitcnt(WCNT_LGKM0_ONLY);
      __builtin_amdgcn_s_barrier();
      short* res = (short*)Abuf[nb];
#pragma unroll
      for (int mt = 0; mt < 2; ++mt)
#pragma unroll
        for (int reg = 0; reg < 4; ++reg) {
          int lrow = rh*32 + mt*16 + qd*4 + reg;
#pragma unroll
          for (int ct = 0; ct < 4; ++ct)
            res[lrow*136 + cg*64 + ct*16 + ln] = f2s(vreg[mt][reg][ct]);
        }
      __builtin_amdgcn_s_waitcnt(WCNT_LGKM0_ONLY);
      __builtin_amdgcn_s_barrier();
#pragma unroll
      for (int i = 0; i < 4; ++i) {
        int g = i * 256 + tid;
        int row = g >> 4, ch = g & 15;
        *(uint4*)((short*)m + (size_t)(e0 + row)*128 + ch*8) =
            *(const uint4*)((const char*)Abuf[nb] + row*272 + ch*16);
      }
      __builtin_amdgcn_s_waitcnt(WCNT_LGKM0_ONLY);
      __builtin_amdgcn_s_barrier();
    } else {
      __builtin_amdgcn_s_waitcnt(WCNT_LGKM0_ONLY);
      __builtin_amdgcn_s_barrier();
    }
  }
}

// ===== fused msg+segsum v12: ONE barrier/step. Wave-private gate (pitch 36,
// 2-way-free banks) + wave-private Pt synced by lgkmcnt+sched_barrier only.
// vmcnt ledger fixed: dn issued BEFORE the Mb DMAs so its use-wait never
// drains them; DMA issued post-barrier (dbuf-safe with a single barrier).
__global__ __launch_bounds__(256, 3) void k_msgagg(
    const __hip_bfloat16* __restrict__ m, const float* __restrict__ dist,
    const __hip_bfloat16* __restrict__ WmT, const float* __restrict__ bm,
    const float* __restrict__ Tg, const int* __restrict__ dst,
    __hip_bfloat16* __restrict__ aggP) {
  __shared__ __align__(16) char gateraw[4 * 32 * 36 * 4];  // 18.0 KB gate / epi tile
  __shared__ __align__(16) char Mb[2][8 * CHB];            // 16.6 KB (32 rows dbuf)
  __shared__ short Pt[128 * 40];                           // 10.0 KB  P^T, swz
  __shared__ int dstS[640];                                //  2.5 KB
  const int tid = threadIdx.x;
  const int c  = blockIdx.x >> 1, pq = blockIdx.x & 1;
  const int w = tid >> 6, lane = tid & 63, ln = lane & 15, qd = lane >> 4;
  const int er = lane & 31, ch = lane >> 5;          // wave-private gate producer
  const int e_loc = lane >> 4;
  const int sgc = (lane & 15) ^ (e_loc << 2);        // pre-swizzled source col-group
  const int sw8 = (ln & 3) << 3;                     // Pt k-XOR swizzle

  float* gateW = (float*)gateraw + w * 32 * 36;      // this wave's [32][36] slice

  const int ebase = c * 1280 + pq * 640;

  float bias2[2];
#pragma unroll
  for (int ct = 0; ct < 2; ++ct) bias2[ct] = bm[w*32 + ct*16 + ln];

  // loop-invariant B fragments: wave owns cols [w*32, w*32+32)
  short8 Bf[2][4];
#pragma unroll
  for (int ct = 0; ct < 2; ++ct) {
    const short* bp = (const short*)WmT + (size_t)(w*32 + ct*16 + ln)*128 + qd*8;
#pragma unroll
    for (int ks = 0; ks < 4; ++ks) Bf[ct][ks] = *(const short8*)(bp + ks*32);
  }

  // ---- stage dst (640 edges, block-shared read-only after prologue) ----
  for (int i = tid; i < 640; i += 256) dstS[i] = dst[ebase + i] & 63;

  // ---- prologue: gate(0) (wave-private), dn, then Mb[0] DMA LAST ----
  float4 ta[4], tb[4]; float frc, msk;
  {
    float d0 = dist[ebase + er];
    msk = (d0 < CUT_F) ? 1.f : 0.f;
    float x = fminf(d0, CUT_F) * ((float)(DQ - 1) / CUT_F);
    int i0 = (int)x; if (i0 > DQ-2) i0 = DQ-2;
    frc = x - (float)i0;
    const float* tp = Tg + (size_t)i0*128 + w*32 + ch*16;
#pragma unroll
    for (int j = 0; j < 4; ++j) {
      ta[j] = *(const float4*)(tp + j*4);
      tb[j] = *(const float4*)(tp + 128 + j*4);
    }
  }
#pragma unroll
  for (int j = 0; j < 4; ++j) {
    float4 g;
    g.x = msk * fmaf(frc, tb[j].x - ta[j].x, ta[j].x);
    g.y = msk * fmaf(frc, tb[j].y - ta[j].y, ta[j].y);
    g.z = msk * fmaf(frc, tb[j].z - ta[j].z, ta[j].z);
    g.w = msk * fmaf(frc, tb[j].w - ta[j].w, ta[j].w);
    *(float4*)&gateW[er*36 + ch*16 + j*4] = g;
  }
  float dn = dist[ebase + 32 + er];                  // BEFORE DMA: its use-wait
#pragma unroll                                        // leaves the DMAs in flight
  for (int t = 0; t < 2; ++t) {
    int chunk = w*2 + t;
    const short* gp = (const short*)m + (size_t)(ebase + chunk*4 + e_loc)*128 + sgc*8;
    DMA16(gp, Mb[0] + chunk*CHB);
  }
  __builtin_amdgcn_s_waitcnt(WCNT_LGKM0_ONLY);       // dstS visible (vm NOT drained)
  __builtin_amdgcn_s_barrier();

  f32x4 accA[4][2];
#pragma unroll
  for (int rt = 0; rt < 4; ++rt)
#pragma unroll
    for (int ct = 0; ct < 2; ++ct) accA[rt][ct] = (f32x4){0,0,0,0};

  for (int s = 0; s < 20; ++s) {
    const int e0 = ebase + s*32;

    if (s < 19) {
      // consume dn (compiler wait: vmcnt(2) -> Mb[s] DMAs stay in flight)
      msk = (dn < CUT_F) ? 1.f : 0.f;
      float x = fminf(dn, CUT_F) * ((float)(DQ - 1) / CUT_F);
      int i0 = (int)x; if (i0 > DQ-2) i0 = DQ-2;
      frc = x - (float)i0;
      const float* tp = Tg + (size_t)i0*128 + w*32 + ch*16;
#pragma unroll
      for (int j = 0; j < 4; ++j) {
        ta[j] = *(const float4*)(tp + j*4);          // 8 vm for gate(s+1)
        tb[j] = *(const float4*)(tp + 128 + j*4);
      }
      if (s < 18) {
        dn = dist[e0 + 64 + er];                     // 1 vm
        __builtin_amdgcn_s_waitcnt(WCNT_VM9_LGKM0);  // drain exactly Mb[s]'s 2 DMAs
      } else {
        __builtin_amdgcn_s_waitcnt(WCNT_VM8_LGKM0);
      }
    } else {
      __builtin_amdgcn_s_waitcnt(WCNT_VM0_LGKM0);
    }
    __builtin_amdgcn_s_barrier();   // the ONLY barrier per step: Mb[s] ready

    if (s < 19) {
      // issue next-step DMA post-barrier (all waves past Mb[s-1] reads -> dbuf safe)
#pragma unroll
      for (int t = 0; t < 2; ++t) {
        int chunk = w*2 + t;
        const short* gp = (const short*)m + (size_t)(e0 + 32 + chunk*4 + e_loc)*128 + sgc*8;
        DMA16(gp, Mb[(s+1) & 1] + chunk*CHB);
      }
    }

    // ---- msg = relu(m @ Wmsg + b): A from Mb (swizzled), B in regs ----
    const char* Ms = Mb[s & 1];
    short8 am[2][4];
#pragma unroll
    for (int et = 0; et < 2; ++et) {
      int r = et*16 + ln;
      const char* rp = Ms + (r>>2)*CHB + (r&3)*256;
      const int sx = (r & 3) << 2;
#pragma unroll
      for (int ks = 0; ks < 4; ++ks)
        am[et][ks] = *(const short8*)(rp + (((ks*4 + qd) ^ sx) << 4));
    }

    f32x4 acc[2][2];
#pragma unroll
    for (int et = 0; et < 2; ++et)
#pragma unroll
      for (int ct = 0; ct < 2; ++ct) acc[et][ct] = (f32x4){0,0,0,0};
#pragma unroll
    for (int ks = 0; ks < 4; ++ks)
#pragma unroll
      for (int et = 0; et < 2; ++et)
#pragma unroll
        for (int ct = 0; ct < 2; ++ct)
          acc[et][ct] = __builtin_amdgcn_mfma_f32_16x16x32_bf16(
              am[et][ks], Bf[ct][ks], acc[et][ct], 0,0,0);

    // ---- P = relu(msg+bias)*gate -> Pt[col][k] (wave-private regions) ----
#pragma unroll
    for (int et = 0; et < 2; ++et)
#pragma unroll
      for (int ct = 0; ct < 2; ++ct) {
        const int col = w*32 + ct*16 + ln;
        float p[4];
#pragma unroll
        for (int reg = 0; reg < 4; ++reg) {
          const int erow = et*16 + qd*4 + reg;
          p[reg] = fmaxf(acc[et][ct][reg] + bias2[ct], 0.f)
                   * gateW[erow*36 + ct*16 + ln];
        }
        unsigned u01 = (unsigned)(unsigned short)f2s(p[0]) |
                       ((unsigned)(unsigned short)f2s(p[1]) << 16);
        unsigned u23 = (unsigned)(unsigned short)f2s(p[2]) |
                       ((unsigned)(unsigned short)f2s(p[3]) << 16);
        const int a0 = col*40 + ((et*16 + qd*4) ^ sw8);
        *(unsigned*)&Pt[a0]     = u01;
        *(unsigned*)&Pt[a0 + 2] = u23;
      }
    // Pt is wave-private: within-wave LDS ordering only (rule-18 fence)
    __builtin_amdgcn_s_waitcnt(WCNT_LGKM0_ONLY);
    __builtin_amdgcn_sched_barrier(0);

    // ---- segsum: accA += onehot(dst) @ P ----
    int dvj[8];
#pragma unroll
    for (int j = 0; j < 8; ++j) dvj[j] = dstS[s*32 + qd*8 + j];
    short8 pb0 = *(const short8*)&Pt[(w*32 + 0*16 + ln)*40 + ((qd*8) ^ sw8)];
    short8 pb1 = *(const short8*)&Pt[(w*32 + 1*16 + ln)*40 + ((qd*8) ^ sw8)];
#pragma unroll
    for (int rt = 0; rt < 4; ++rt) {
      short8 oh;
#pragma unroll
      for (int j = 0; j < 8; ++j)
        oh[j] = (dvj[j] == rt*16 + ln) ? (short)0x3F80 : (short)0;
      accA[rt][0] = __builtin_amdgcn_mfma_f32_16x16x32_bf16(oh, pb0, accA[rt][0], 0,0,0);
      accA[rt][1] = __builtin_amdgcn_mfma_f32_16x16x32_bf16(oh, pb1, accA[rt][1], 0,0,0);
    }

    // ---- gate(s+1): wave-private write; read next step after top lgkm(0) ----
    if (s < 19) {
#pragma unroll
      for (int j = 0; j < 4; ++j) {
        float4 g;
        g.x = msk * fmaf(frc, tb[j].x - ta[j].x, ta[j].x);
        g.y = msk * fmaf(frc, tb[j].y - ta[j].y, ta[j].y);
        g.z = msk * fmaf(frc, tb[j].z - ta[j].z, ta[j].z);
        g.w = msk * fmaf(frc, tb[j].w - ta[j].w, ta[j].w);
        *(float4*)&gateW[er*36 + ch*16 + j*4] = g;
      }
    }
  }

  // ---- epilogue: barrier (gate reads done block-wide), then LDS transpose
  // into gateraw as tbuf [64][140] shorts (17.9 KB fits), full-line stores.
  __builtin_amdgcn_s_waitcnt(WCNT_LGKM0_ONLY);
  __builtin_amdgcn_s_barrier();
  short* tbuf = (short*)gateraw;
#pragma unroll
  for (int rt = 0; rt < 4; ++rt)
#pragma unroll
    for (int ct = 0; ct < 2; ++ct) {
      const int col = w*32 + ct*16 + ln;
#pragma unroll
      for (int reg = 0; reg < 4; ++reg)
        tbuf[(rt*16 + qd*4 + reg)*140 + col] = f2s(accA[rt][ct][reg]);
    }
  __builtin_amdgcn_s_waitcnt(WCNT_LGKM0_ONLY);
  __builtin_amdgcn_s_barrier();
  {
    __hip_bfloat16* outp = aggP + ((size_t)pq * NATOMS + c * 64) * HID;
    const int r = tid >> 2, cq = tid & 3;
#pragma unroll
    for (int hh = 0; hh < 4; ++hh) {
      short8 o = *(const short8*)&tbuf[r*140 + cq*32 + hh*8];
      *(uint4*)((short*)outp + (size_t)r*HID + cq*32 + hh*8) = *(uint4*)&o;
    }
  }
}

// ============ FUSED fc+uv: h += relu(sum(slices)@Wa + ba); then
// u = h@Wu, v = h@Wv via LDS C->A layout round-trip. 64 rows/block.
__global__ __launch_bounds__(256) void k_fcuv(
    const __hip_bfloat16* __restrict__ slices,
    const __hip_bfloat16* __restrict__ WTa, const float* __restrict__ ba,
    float* __restrict__ h, __hip_bfloat16* __restrict__ h_bf,
    const __hip_bfloat16* __restrict__ WTu, const __hip_bfloat16* __restrict__ WTv,
    __hip_bfloat16* __restrict__ uo, __hip_bfloat16* __restrict__ vo) {
  __shared__ short ht[64 * 136];   // 17.4 KB fresh-h tile (row pitch 136)
  const int tid = threadIdx.x;
  const int w = tid >> 6, lane = tid & 63, ln = lane & 15, qd = lane >> 4;
  const int row0w = blockIdx.x * 64 + w * 16;
  const int arow = row0w + ln;

  // ---- phase 1: h update (slice sum -> MFMA -> residual) ----
  short8 af[4];
#pragma unroll
  for (int ks = 0; ks < 4; ++ks) {
    float s[8] = {0,0,0,0,0,0,0,0};
#pragma unroll
    for (int p = 0; p < NPART; ++p) {
      short8 v = *(const short8*)((const short*)slices +
                   (size_t)p*NATOMS*128 + (size_t)arow*128 + qd*8 + ks*32);
#pragma unroll
      for (int u = 0; u < 8; ++u) s[u] += s2f(v[u]);
    }
    af[ks] = (short8){f2s(s[0]),f2s(s[1]),f2s(s[2]),f2s(s[3]),
                      f2s(s[4]),f2s(s[5]),f2s(s[6]),f2s(s[7])};
  }

  const short* Wb = (const short*)WTa + ln*128 + qd*8;
  f32x4 acc[8];
#pragma unroll
  for (int ct = 0; ct < 8; ++ct) acc[ct] = (f32x4){0,0,0,0};
#pragma unroll
  for (int ct = 0; ct < 8; ++ct)
#pragma unroll
    for (int ks = 0; ks < 4; ++ks)
      acc[ct] = __builtin_amdgcn_mfma_f32_16x16x32_bf16(af[ks],
                  *(const short8*)(Wb + ct*16*128 + ks*32), acc[ct], 0,0,0);

#pragma unroll
  for (int ct = 0; ct < 8; ++ct) {
    int col = ct*16 + ln;
    float bias = ba[col];
#pragma unroll
    for (int reg = 0; reg < 4; ++reg) {
      int lrow = w*16 + qd*4 + reg;          // row within block's 64
      size_t o = (size_t)(blockIdx.x*64 + lrow)*128 + col;
      float v = fmaxf(acc[ct][reg] + bias, 0.f) + h[o];
      h[o] = v;
      short hb = f2s(v);
      h_bf[o] = *(__hip_bfloat16*)&hb;
      ht[lrow*136 + col] = hb;
    }
  }
  __syncthreads();

  // ---- phase 2: dual projection from LDS tile ----
  short8 ah[4];
  const short* ph = &ht[(w*16 + ln)*136 + qd*8];
#pragma unroll
  for (int ks = 0; ks < 4; ++ks) ah[ks] = *(const short8*)(ph + ks*32);

  f32x4 a1[8], a2[8];
#pragma unroll
  for (int ct = 0; ct < 8; ++ct) { a1[ct] = (f32x4){0,0,0,0}; a2[ct] = (f32x4){0,0,0,0}; }
#pragma unroll
  for (int ct = 0; ct < 8; ++ct) {
    const short* b1 = (const short*)WTu + (ct*16 + ln)*128 + qd*8;
    const short* b2 = (const short*)WTv + (ct*16 + ln)*128 + qd*8;
#pragma unroll
    for (int ks = 0; ks < 4; ++ks) {
      a1[ct] = __builtin_amdgcn_mfma_f32_16x16x32_bf16(ah[ks], *(const short8*)(b1 + ks*32), a1[ct], 0,0,0);
      a2[ct] = __builtin_amdgcn_mfma_f32_16x16x32_bf16(ah[ks], *(const short8*)(b2 + ks*32), a2[ct], 0,0,0);
    }
  }
#pragma unroll
  for (int ct = 0; ct < 8; ++ct) {
    int col = ct*16 + ln;
#pragma unroll
    for (int reg = 0; reg < 4; ++reg) {
      size_t o = (size_t)(row0w + qd*4 + reg)*128 + col;
      uo[o] = f2bf(a1[ct][reg]);
      vo[o] = f2bf(a2[ct][reg]);
    }
  }
}

// ============ FUSED head: a1 = relu(h@W1+b1); a2 = relu(a1@W2+b2);
// out = a2@W3 + b3  (fc3 reduced in-wave). 64 rows/block.
__global__ __launch_bounds__(256) void k_head(
    const __hip_bfloat16* __restrict__ h_bf,
    const __hip_bfloat16* __restrict__ WT1, const float* __restrict__ b1,
    const __hip_bfloat16* __restrict__ WT2, const float* __restrict__ b2,
    const float* __restrict__ W3, const float* __restrict__ b3,
    float* __restrict__ out) {
  __shared__ short t1[64 * 136];   // 17.4 KB a1 tile
  const int tid = threadIdx.x;
  const int w = tid >> 6, lane = tid & 63, ln = lane & 15, qd = lane >> 4;
  const int row0w = blockIdx.x * 64 + w * 16;
  const int arow = row0w + ln;

  // ---- fc1 ----
  short8 af[4];
  const short* pa = (const short*)h_bf + (size_t)arow*128 + qd*8;
#pragma unroll
  for (int ks = 0; ks < 4; ++ks) af[ks] = *(const short8*)(pa + ks*32);

  f32x4 acc[8];
#pragma unroll
  for (int ct = 0; ct < 8; ++ct) acc[ct] = (f32x4){0,0,0,0};
#pragma unroll
  for (int ct = 0; ct < 8; ++ct) {
    const short* bb = (const short*)WT1 + (ct*16 + ln)*128 + qd*8;
#pragma unroll
    for (int ks = 0; ks < 4; ++ks)
      acc[ct] = __builtin_amdgcn_mfma_f32_16x16x32_bf16(af[ks],
                  *(const short8*)(bb + ks*32), acc[ct], 0,0,0);
  }
#pragma unroll
  for (int ct = 0; ct < 8; ++ct) {
    int col = ct*16 + ln;
    float bias = b1[col];
#pragma unroll
    for (int reg = 0; reg < 4; ++reg) {
      int lrow = w*16 + qd*4 + reg;
      t1[lrow*136 + col] = f2s(fmaxf(acc[ct][reg] + bias, 0.f));
    }
  }
  __syncthreads();

  // ---- fc2 ----
  short8 a1f[4];
  const short* p1 = &t1[(w*16 + ln)*136 + qd*8];
#pragma unroll
  for (int ks = 0; ks < 4; ++ks) a1f[ks] = *(const short8*)(p1 + ks*32);

  f32x4 acc2[8];
#pragma unroll
  for (int ct = 0; ct < 8; ++ct) acc2[ct] = (f32x4){0,0,0,0};
#pragma unroll
  for (int ct = 0; ct < 8; ++ct) {
    const short* bb = (const short*)WT2 + (ct*16 + ln)*128 + qd*8;
#pragma unroll
    for (int ks = 0; ks < 4; ++ks)
      acc2[ct] = __builtin_amdgcn_mfma_f32_16x16x32_bf16(a1f[ks],
                   *(const short8*)(bb + ks*32), acc2[ct], 0,0,0);
  }

  // ---- fc3 (in-register): per (reg): p_j = sum_ct a2 * W3[col][j] ----
  float w3a[8], w3b[8];
#pragma unroll
  for (int ct = 0; ct < 8; ++ct) {
    int col = ct*16 + ln;
    w3a[ct] = W3[col*2+0];
    w3b[ct] = W3[col*2+1];
  }
#pragma unroll
  for (int reg = 0; reg < 4; ++reg) {
    float p0 = 0.f, p1v = 0.f;
#pragma unroll
    for (int ct = 0; ct < 8; ++ct) {
      float a2v = fmaxf(acc2[ct][reg] + b2[ct*16 + ln], 0.f);
      p0  = fmaf(a2v, w3a[ct], p0);
      p1v = fmaf(a2v, w3b[ct], p1v);
    }
    p0  += __shfl_xor(p0, 1, 64);  p1v += __shfl_xor(p1v, 1, 64);
    p0  += __shfl_xor(p0, 2, 64);  p1v += __shfl_xor(p1v, 2, 64);
    p0  += __shfl_xor(p0, 4, 64);  p1v += __shfl_xor(p1v, 4, 64);
    p0  += __shfl_xor(p0, 8, 64);  p1v += __shfl_xor(p1v, 8, 64);
    if (ln == 0) {
      int row = row0w + qd*4 + reg;
      out[row*2+0] = p0 + b3[0];
      out[row*2+1] = p1v + b3[1];
    }
  }
}

// ----------------------------------- pred_cart = segsum(f*unit) per crystal
__global__ void k_pcart(const float* __restrict__ f, const float* __restrict__ unit,
                        const int* __restrict__ dst, float* __restrict__ out) {
  __shared__ float acc[AATOMS * 3];
  int c = blockIdx.x, tid = threadIdx.x;  // 256 threads
  if (tid < AATOMS*3) acc[tid] = 0.f;
  __syncthreads();
  for (int t = tid; t < 1280; t += 256) {
    int e = c*1280 + t;
    int d = dst[e] & 63;
    float fv = f[e];
    atomicAdd(&acc[d*3+0], fv * unit[e*3+0]);
    atomicAdd(&acc[d*3+1], fv * unit[e*3+1]);
    atomicAdd(&acc[d*3+2], fv * unit[e*3+2]);
  }
  __syncthreads();
  if (tid < AATOMS*3) out[c*AATOMS*3 + tid] = acc[tid];
}

extern "C" void kernel_launch(void* const* d_in, const int* in_sizes, int n_in,
                              void* d_out, int out_size, void* d_ws, size_t ws_size,
                              hipStream_t stream) {
  const float* z        = (const float*)d_in[0];
  const float* frac     = (const float*)d_in[1];
  const float* lengths  = (const float*)d_in[2];
  const float* angles   = (const float*)d_in[3];
  const int*   atype    = (const int*)  d_in[4];
  const int*   src      = (const int*)  d_in[5];
  const int*   dst      = (const int*)  d_in[6];
  const float* emb      = (const float*)d_in[7];
  const float* W_in     = (const float*)d_in[8];
  const float* b_in     = (const float*)d_in[9];
  const float* W_edge   = (const float*)d_in[10];
  const float* b_edge   = (const float*)d_in[11];
  const float* Wb_rbf   = (const float*)d_in[12];
  const float* Wb_msg   = (const float*)d_in[13];
  const float* bb_msg   = (const float*)d_in[14];
  const float* Wb_atom  = (const float*)d_in[15];
  const float* bb_atom  = (const float*)d_in[16];
  const float* Wb_upd   = (const float*)d_in[17];
  const float* bb_upd   = (const float*)d_in[18];
  const float* W_force  = (const float*)d_in[19];
  const float* b_force  = (const float*)d_in[20];
  const float* W_fc1    = (const float*)d_in[21];
  const float* b_fc1    = (const float*)d_in[22];
  const float* W_fc2    = (const float*)d_in[23];
  const float* b_fc2    = (const float*)d_in[24];
  const float* W_fc3    = (const float*)d_in[25];
  const float* b_fc3    = (const float*)d_in[26];

  // ---- workspace layout ----
  char* p = (char*)d_ws;
  float* cart = (float*)p;            p += (size_t)NATOMS*3*4;
  float* unit = (float*)p;            p += (size_t)NEDGE*3*4;
  float* dist = (float*)p;            p += (size_t)NEDGE*4;
  float* h    = (float*)p;            p += (size_t)NATOMS*HID*4;
  float* fbuf = (float*)p;            p += (size_t)NEDGE*4;
  float* T    = (float*)p;            p += (size_t)4*DQ*128*4;
  __hip_bfloat16* h_bf = (__hip_bfloat16*)p; p += (size_t)NATOMS*HID*2;
  __hip_bfloat16* u0t  = (__hip_bfloat16*)p; p += (size_t)NATOMS*HID*2;
  __hip_bfloat16* v0t  = (__hip_bfloat16*)p; p += (size_t)NATOMS*HID*2;
  __hip_bfloat16* uut  = (__hip_bfloat16*)p; p += (size_t)NATOMS*HID*2;
  __hip_bfloat16* vvt  = (__hip_bfloat16*)p; p += (size_t)NATOMS*HID*2;
  __hip_bfloat16* aggP = (__hip_bfloat16*)p; p += (size_t)NPART*NATOMS*HID*2;
  __hip_bfloat16* m    = (__hip_bfloat16*)p; p += (size_t)NEDGE*HID*2;
  __hip_bfloat16* WT   = (__hip_bfloat16*)p; p += (size_t)360448*2;

  __hip_bfloat16* WT_in   = WT;
  __hip_bfloat16* WTK     = WT + 49152;          // 19 K=128 blocks
  __hip_bfloat16* WT_u0   = WTK + 0*16384;
  __hip_bfloat16* WT_v0   = WTK + 1*16384;
  __hip_bfloat16* WT_updB = WTK + 2*16384;       // (uu,vv,mm) x 3
  __hip_bfloat16* WT_msg  = WTK + 11*16384;
  __hip_bfloat16* WT_atom = WTK + 14*16384;
  __hip_bfloat16* WT_fc1  = WTK + 17*16384;
  __hip_bfloat16* WT_fc2  = WTK + 18*16384;

  float* out_cart = (float*)d_out;
  float* out_at   = out_cart + NATOMS*3;

  k_wcast<<<1408, 256, 0, stream>>>(W_in, W_edge, Wb_upd, Wb_msg, Wb_atom,
                                    W_fc1, W_fc2, WT);
  k_tab<<<DQ, 128, 0, stream>>>(W_edge, Wb_rbf, T);
  k_cart<<<NATOMS/256, 256, 0, stream>>>(frac, lengths, angles, cart);
  k_edge<<<NEDGE/256, 256, 0, stream>>>(cart, src, dst, unit, dist, b_force, fbuf);
  k_hm<<<NATOMS/64, 256, 0, stream>>>(atype, z, emb, WT_in, b_in, h, h_bf);
  k_uv2<<<NATOMS/64, 256, 0, stream>>>(h_bf, WT_u0, WT_v0, u0t, v0t);
  k_minit<<<NEDGE/64, 256, 0, stream>>>(src, dst, dist, u0t, v0t, T, b_edge, m);

  for (int i = 0; i < NBLK; ++i) {
    k_msgagg<<<NCRYST*NPART, 256, 0, stream>>>(m, dist, WT_msg + i*16384,
                                               bb_msg + i*HID, T + (size_t)(1+i)*DQ*128,
                                               dst, aggP);
    k_fcuv<<<NATOMS/64, 256, 0, stream>>>(aggP, WT_atom + i*16384, bb_atom + i*HID,
                                          h, h_bf,
                                          WT_updB + (3*i+0)*16384,
                                          WT_updB + (3*i+1)*16384, uut, vvt);
    if (i < NBLK-1) {
      k_eup<1><<<NCRYST*2, 256, 0, stream>>>(src, dst, m, uut, vvt,
                                             WT_updB + (3*i+2)*16384, bb_upd + i*HID,
                                             nullptr, nullptr);
    } else {
      k_eup<2><<<NCRYST*2, 256, 0, stream>>>(src, dst, m, uut, vvt,
                                             WT_updB + (3*i+2)*16384, bb_upd + i*HID,
                                             W_force, fbuf);
    }
  }
  k_pcart<<<NCRYST, 256, 0, stream>>>(fbuf, unit, dst, out_cart);
  k_head<<<NATOMS/64, 256, 0, stream>>>(h_bf, WT_fc1, b_fc1, WT_fc2, b_fc2,
                                        W_fc3, b_fc3, out_at);
}

// Round 8
// 602.117 us; speedup vs baseline: 1.2685x; 1.2685x over previous
//
#include <hip/hip_runtime.h>
#include <hip/hip_bf16.h>

#define NCRYST 256
#define AATOMS 64
#define KNBR   20
#define HID    128
#define LAT    256
#define NRBF   128
#define NBLK   3
#define NATOMS (NCRYST * AATOMS)   // 16384
#define NEDGE  (NATOMS * KNBR)     // 327680
#define NPART  2                   // agg partial slices per crystal
#define DQ     4096                // dist-table knots over [0, CUT]
#define PI_F   3.14159265358979323846f
#define CUT_F  6.0f
#define CHB    1040                // LDS A chunk stride: 1024 B payload + 16 B pad

typedef short short8 __attribute__((ext_vector_type(8)));   // 8 bf16 (4 VGPRs)
typedef float f32x4  __attribute__((ext_vector_type(4)));   // MFMA C/D

__device__ __forceinline__ float bf2f(__hip_bfloat16 x) { return __bfloat162float(x); }
__device__ __forceinline__ __hip_bfloat16 f2bf(float x) { return __float2bfloat16(x); }
__device__ __forceinline__ float s2f(short x) {
  return __uint_as_float(((unsigned)(unsigned short)x) << 16);
}
__device__ __forceinline__ short f2s(float x) {
  union { short s; __hip_bfloat16 b; } u; u.b = f2bf(x); return u.s;
}

#define DMA16(gptr, lptr) __builtin_amdgcn_global_load_lds( \
    (const __attribute__((address_space(1))) void*)(gptr),  \
    (__attribute__((address_space(3))) void*)(lptr), 16, 0, 0)

// s_waitcnt immediates: vm = bits[3:0], exp = bits[6:4] (7 = no wait),
// lgkm = bits[11:8] (0xF = no wait), vm-high = bits[15:14].
#define WCNT_VM11_LGKM0 0x007B
#define WCNT_VM10_LGKM0 0x007A
#define WCNT_VM4_LGKM0  0x0074
#define WCNT_VM0_LGKM0  0x0070
#define WCNT_LGKM0_ONLY 0xC07F   // vmcnt=63 (no wait), lgkmcnt(0)

// ---------------------------------------------------------------- cart coords
__global__ void k_cart(const float* __restrict__ frac, const float* __restrict__ lengths,
                       const float* __restrict__ angles, float* __restrict__ cart) {
  int atom = blockIdx.x * blockDim.x + threadIdx.x;
  if (atom >= NATOMS) return;
  int c = atom >> 6;
  float al = angles[c*3+0] * (PI_F/180.f);
  float be = angles[c*3+1] * (PI_F/180.f);
  float ga = angles[c*3+2] * (PI_F/180.f);
  float ca = cosf(al), cb = cosf(be), cg = cosf(ga), sg = sinf(ga);
  float a = lengths[c*3+0], b = lengths[c*3+1], cl = lengths[c*3+2];
  float cx = cl * cb;
  float cy = cl * (ca - cb*cg) / sg;
  float cz = sqrtf(fmaxf(cl*cl - cx*cx - cy*cy, 1e-8f));
  float f0 = frac[atom*3+0], f1 = frac[atom*3+1], f2 = frac[atom*3+2];
  cart[atom*3+0] = f0*a + f1*(b*cg) + f2*cx;
  cart[atom*3+1] = f1*(b*sg) + f2*cy;
  cart[atom*3+2] = f2*cz;
}

// ---------------- edge geometry: unit + dist; also init fbuf[e] = b_force
__global__ void k_edge(const float* __restrict__ cart, const int* __restrict__ src,
                       const int* __restrict__ dst, float* __restrict__ unit,
                       float* __restrict__ dist, const float* __restrict__ b_force,
                       float* __restrict__ fbuf) {
  int e = blockIdx.x * blockDim.x + threadIdx.x;
  if (e >= NEDGE) return;
  int s = src[e], d = dst[e];
  float dx = cart[d*3+0] - cart[s*3+0];
  float dy = cart[d*3+1] - cart[s*3+1];
  float dz = cart[d*3+2] - cart[s*3+2];
  float dd = sqrtf(dx*dx + dy*dy + dz*dz + 1e-12f);
  float inv = 1.f / dd;
  dist[e] = dd;
  unit[e*3+0] = dx*inv; unit[e*3+1] = dy*inv; unit[e*3+2] = dz*inv;
  fbuf[e] = b_force[0];
}

// ---------------- dist tables: T[0]=rbf@W_edge[256:384], T[1+i]=rbf@Wb_rbf[i]
__global__ __launch_bounds__(128) void k_tab(const float* __restrict__ W_edge,
                                             const float* __restrict__ Wb_rbf,
                                             float* __restrict__ T) {
  int q = blockIdx.x, n = threadIdx.x;
  __shared__ float rv[128];
  float d = (float)q * (CUT_F / (float)(DQ - 1));
  float env = 0.5f * (cosf(PI_F * fminf(d * (1.f/CUT_F), 1.f)) + 1.f);
  float t = (d - (float)n * (CUT_F/(NRBF-1))) * ((NRBF-1)/CUT_F);
  rv[n] = expf(-t*t) * env;
  __syncthreads();
  float a0 = 0.f, a1 = 0.f, a2 = 0.f, a3 = 0.f;
  for (int j = 0; j < 128; ++j) {
    float r = rv[j];
    a0 = fmaf(r, W_edge[(256 + j)*128 + n], a0);
    a1 = fmaf(r, Wb_rbf[0*16384 + j*128 + n], a1);
    a2 = fmaf(r, Wb_rbf[1*16384 + j*128 + n], a2);
    a3 = fmaf(r, Wb_rbf[2*16384 + j*128 + n], a3);
  }
  T[(0*DQ + q)*128 + n] = a0;
  T[(1*DQ + q)*128 + n] = a1;
  T[(2*DQ + q)*128 + n] = a2;
  T[(3*DQ + q)*128 + n] = a3;
}

// ----------------- weights -> bf16 n-major K=128 blocks (W_in stays K=384)
__global__ void k_wcast(const float* __restrict__ W_in, const float* __restrict__ W_edge,
                        const float* __restrict__ Wb_upd, const float* __restrict__ Wb_msg,
                        const float* __restrict__ Wb_atom, const float* __restrict__ W_fc1,
                        const float* __restrict__ W_fc2, __hip_bfloat16* __restrict__ WT) {
  int idx = blockIdx.x * 256 + threadIdx.x;
  if (idx >= 360448) return;
  if (idx < 49152) {
    int n = idx / 384, k = idx % 384;
    WT[idx] = f2bf(W_in[k*128 + n]);
    return;
  }
  int t = idx - 49152;
  int b = t >> 14, q = t & 16383;
  int n = q >> 7, k = q & 127;
  const float* S; int krow;
  if (b == 0)       { S = W_edge; krow = k; }
  else if (b == 1)  { S = W_edge; krow = 128 + k; }
  else if (b <= 10) { int i = (b-2)/3, part = (b-2)%3;
                      S = Wb_upd + i*49152; krow = part*128 + k; }
  else if (b <= 13) { S = Wb_msg + (b-11)*16384; krow = k; }
  else if (b <= 16) { S = Wb_atom + (b-14)*16384; krow = k; }
  else if (b == 17) { S = W_fc1; krow = k; }
  else              { S = W_fc2; krow = k; }
  WT[idx] = f2bf(S[krow*128 + n]);
}

// ============ MFMA h: h = relu([emb[atype]|z]@W_in + b), 64 rows/block
__global__ __launch_bounds__(256) void k_hm(
    const int* __restrict__ atype, const float* __restrict__ z,
    const float* __restrict__ emb, const __hip_bfloat16* __restrict__ WTin,
    const float* __restrict__ b, float* __restrict__ h,
    __hip_bfloat16* __restrict__ h_bf) {
  const int tid = threadIdx.x;
  const int w = tid >> 6, lane = tid & 63, ln = lane & 15, qd = lane >> 4;
  const int row0w = blockIdx.x * 64 + w * 16;
  const int arow = row0w + ln;
  const float* esrc = emb + (size_t)atype[arow] * 128;
  const float* zsrc = z + (size_t)(arow >> 6) * LAT;

  short8 af[12];
#pragma unroll
  for (int ks = 0; ks < 4; ++ks) {
    float4 v0 = *(const float4*)(esrc + ks*32 + qd*8);
    float4 v1 = *(const float4*)(esrc + ks*32 + qd*8 + 4);
    af[ks] = (short8){f2s(v0.x),f2s(v0.y),f2s(v0.z),f2s(v0.w),
                      f2s(v1.x),f2s(v1.y),f2s(v1.z),f2s(v1.w)};
  }
#pragma unroll
  for (int ks = 4; ks < 12; ++ks) {
    float4 v0 = *(const float4*)(zsrc + (ks-4)*32 + qd*8);
    float4 v1 = *(const float4*)(zsrc + (ks-4)*32 + qd*8 + 4);
    af[ks] = (short8){f2s(v0.x),f2s(v0.y),f2s(v0.z),f2s(v0.w),
                      f2s(v1.x),f2s(v1.y),f2s(v1.z),f2s(v1.w)};
  }

  const short* Wb = (const short*)WTin + ln*384 + qd*8;
  f32x4 acc[8];
#pragma unroll
  for (int ct = 0; ct < 8; ++ct) acc[ct] = (f32x4){0,0,0,0};
#pragma unroll
  for (int ks = 0; ks < 12; ++ks)
#pragma unroll
    for (int ct = 0; ct < 8; ++ct)
      acc[ct] = __builtin_amdgcn_mfma_f32_16x16x32_bf16(af[ks],
                  *(const short8*)(Wb + ct*16*384 + ks*32), acc[ct], 0,0,0);

#pragma unroll
  for (int ct = 0; ct < 8; ++ct) {
    int col = ct*16 + ln;
    float bias = b[col];
#pragma unroll
    for (int reg = 0; reg < 4; ++reg) {
      int crow = row0w + qd*4 + reg;
      float v = fmaxf(acc[ct][reg] + bias, 0.f);
      size_t o = (size_t)crow*128 + col;
      h[o] = v;
      h_bf[o] = f2bf(v);
    }
  }
}

// ============ dual projection: O1 = A@WT1, O2 = A@WT2 (no bias/relu, bf16)
__global__ __launch_bounds__(256) void k_uv2(
    const __hip_bfloat16* __restrict__ A,
    const __hip_bfloat16* __restrict__ WT1, const __hip_bfloat16* __restrict__ WT2,
    __hip_bfloat16* __restrict__ O1, __hip_bfloat16* __restrict__ O2) {
  const int tid = threadIdx.x;
  const int w = tid >> 6, lane = tid & 63, ln = lane & 15, qd = lane >> 4;
  const int row0w = blockIdx.x * 64 + w * 16;
  const int arow = row0w + ln;

  short8 af[4];
  const short* pa = (const short*)A + (size_t)arow*128 + qd*8;
#pragma unroll
  for (int ks = 0; ks < 4; ++ks) af[ks] = *(const short8*)(pa + ks*32);

  f32x4 a1[8], a2[8];
#pragma unroll
  for (int ct = 0; ct < 8; ++ct) { a1[ct] = (f32x4){0,0,0,0}; a2[ct] = (f32x4){0,0,0,0}; }
#pragma unroll
  for (int ct = 0; ct < 8; ++ct) {
    const short* b1 = (const short*)WT1 + (ct*16 + ln)*128 + qd*8;
    const short* b2 = (const short*)WT2 + (ct*16 + ln)*128 + qd*8;
#pragma unroll
    for (int ks = 0; ks < 4; ++ks) {
      a1[ct] = __builtin_amdgcn_mfma_f32_16x16x32_bf16(af[ks], *(const short8*)(b1 + ks*32), a1[ct], 0,0,0);
      a2[ct] = __builtin_amdgcn_mfma_f32_16x16x32_bf16(af[ks], *(const short8*)(b2 + ks*32), a2[ct], 0,0,0);
    }
  }
#pragma unroll
  for (int ct = 0; ct < 8; ++ct) {
    int col = ct*16 + ln;
#pragma unroll
    for (int reg = 0; reg < 4; ++reg) {
      size_t o = (size_t)(row0w + qd*4 + reg)*128 + col;
      O1[o] = f2bf(a1[ct][reg]);
      O2[o] = f2bf(a2[ct][reg]);
    }
  }
}

// ============ m init v2: m = relu(u0[src] + v0[dst] + T0(d) + b)
__global__ __launch_bounds__(256) void k_minit(
    const int* __restrict__ src, const int* __restrict__ dst,
    const float* __restrict__ dist,
    const __hip_bfloat16* __restrict__ u0, const __hip_bfloat16* __restrict__ v0,
    const float* __restrict__ T0, const float* __restrict__ b,
    __hip_bfloat16* __restrict__ m) {
  const int t = threadIdx.x;
  const int li = t & 15, ei = t >> 4;
  float bcol[8];
#pragma unroll
  for (int u = 0; u < 8; ++u) bcol[u] = b[li*8 + u];

  int e[4]; float dd[4]; short8 us[4], vs[4];
#pragma unroll
  for (int g = 0; g < 4; ++g) {
    e[g] = blockIdx.x*64 + g*16 + ei;
    dd[g] = dist[e[g]];
    int s = src[e[g]], d = dst[e[g]];
    us[g] = *(const short8*)((const short*)u0 + (size_t)s*128 + li*8);
    vs[g] = *(const short8*)((const short*)v0 + (size_t)d*128 + li*8);
  }
  float t0v[4][8], t1v[4][8]; float fr[4]; bool in[4];
#pragma unroll
  for (int g = 0; g < 4; ++g) {
    in[g] = dd[g] < CUT_F;
    float x = fminf(dd[g], CUT_F) * ((float)(DQ - 1) / CUT_F);
    int i0 = (int)x;
    fr[g] = x - (float)i0;
    const float* tp = T0 + (size_t)i0*128 + li*8;
    *(float4*)&t0v[g][0] = *(const float4*)tp;
    *(float4*)&t0v[g][4] = *(const float4*)(tp + 4);
    *(float4*)&t1v[g][0] = *(const float4*)(tp + 128);
    *(float4*)&t1v[g][4] = *(const float4*)(tp + 132);
  }
#pragma unroll
  for (int g = 0; g < 4; ++g) {
    short8 o;
#pragma unroll
    for (int u = 0; u < 8; ++u) {
      float tv = in[g] ? fmaf(fr[g], t1v[g][u] - t0v[g][u], t0v[g][u]) : 0.f;
      float v = s2f(us[g][u]) + s2f(vs[g][u]) + tv + bcol[u];
      o[u] = f2s(fmaxf(v, 0.f));
    }
    *(uint4*)((short*)m + (size_t)e[g]*128 + li*8) = *(uint4*)&o;
  }
}

// ============ m update v2: block = (crystal, half), 10 tiles of 64 edges.
// uu[src]+vv[dst] gathers via one-hot MFMA; crystal B-frags in regs once/block.
template<int MODE>
__global__ __launch_bounds__(256) void k_eup(
    const int* __restrict__ src, const int* __restrict__ dst,
    __hip_bfloat16* __restrict__ m,
    const __hip_bfloat16* __restrict__ uu, const __hip_bfloat16* __restrict__ vv,
    const __hip_bfloat16* __restrict__ WTmm, const float* __restrict__ b,
    const float* __restrict__ Wf, float* __restrict__ fout) {
  __shared__ short Bs[128 * 132];                     // 33.8 KB
  __shared__ __align__(16) char Abuf[2][17 * CHB];    // 2 x 17.7 KB
  __shared__ short srcS[640], dstS[640];              //  2.5 KB
  const int tid = threadIdx.x;
  const int w = tid >> 6, lane = tid & 63, ln = lane & 15, qd = lane >> 4;
  const int cg = w & 1, rh = w >> 1;
  const int e_loc = lane >> 4;                        // edge within 4-edge chunk
  const int sgc = (lane & 15) ^ (e_loc << 2);         // pre-swizzled source col-group
  const int cry = blockIdx.x >> 1, half = blockIdx.x & 1;
  const int ebase = cry * 1280 + half * 640;
  const int ca = cry * 64;                            // crystal atom base

#pragma unroll
  for (int i = 0; i < 8; ++i) {
    int g = i * 256 + tid;
    int colb = g >> 4, ch = g & 15;
    *(uint4*)&Bs[colb*132 + ch*8] = ((const uint4*)((const short*)WTmm + colb*128))[ch];
  }
  for (int i = tid; i < 640; i += 256) {
    srcS[i] = (short)(src[ebase + i] & 63);
    dstS[i] = (short)(dst[ebase + i] & 63);
  }

  float bias4[4], wf4[4];
#pragma unroll
  for (int ct = 0; ct < 4; ++ct) bias4[ct] = b[cg*64 + ct*16 + ln];
  if constexpr (MODE == 2) {
#pragma unroll
    for (int ct = 0; ct < 4; ++ct) wf4[ct] = Wf[cg*64 + ct*16 + ln];
  }

  // ---- crystal uu/vv gather B-fragments: B[k=atom][col], regs, once/block ----
  short8 Bu[2][4], Bv[2][4];
#pragma unroll
  for (int ks = 0; ks < 2; ++ks)
#pragma unroll
    for (int ct = 0; ct < 4; ++ct) {
      const int col = cg*64 + ct*16 + ln;
#pragma unroll
      for (int j = 0; j < 8; ++j) {
        const size_t ro = (size_t)(ca + ks*32 + qd*8 + j) * 128 + col;
        Bu[ks][ct][j] = ((const short*)uu)[ro];
        Bv[ks][ct][j] = ((const short*)vv)[ro];
      }
    }

#pragma unroll
  for (int t4 = 0; t4 < 4; ++t4) {
    int chunk = w * 4 + t4;
    const short* gp = (const short*)m + (size_t)(ebase + chunk*4 + e_loc)*128 + sgc*8;
    DMA16(gp, Abuf[0] + chunk * CHB);
  }

  for (int t = 0; t < 10; ++t) {
    const int nb = t & 1;
    if (t < 9) {
#pragma unroll
      for (int t4 = 0; t4 < 4; ++t4) {
        int chunk = w * 4 + t4;
        const short* gp = (const short*)m +
            (size_t)(ebase + (t+1)*64 + chunk*4 + e_loc)*128 + sgc*8;
        DMA16(gp, Abuf[nb^1] + chunk * CHB);
      }
      __builtin_amdgcn_s_waitcnt(WCNT_VM4_LGKM0);   // keep next tile's 4 DMAs
    } else {
      __builtin_amdgcn_s_waitcnt(WCNT_VM0_LGKM0);
    }
    __builtin_amdgcn_s_barrier();

    const char* Ab = Abuf[nb];
    const int e0 = ebase + t*64;
    const int l0 = t*64;

    const int rowA = rh*32 + ln, rowB = rowA + 16;
    const int sa = srcS[l0 + rowA], da = dstS[l0 + rowA];
    const int sb = srcS[l0 + rowB], db = dstS[l0 + rowB];

    f32x4 acc0[4], acc1[4];
#pragma unroll
    for (int ct = 0; ct < 4; ++ct) { acc0[ct] = (f32x4){0,0,0,0}; acc1[ct] = (f32x4){0,0,0,0}; }
    const int sx = (ln & 3) << 2;                     // rowA&3 == rowB&3 == ln&3
#pragma unroll
    for (int ks = 0; ks < 4; ++ks) {
      int slot = ((ks*4 + qd) ^ sx) << 4;
      short8 aA = *(const short8*)(Ab + (rowA>>2)*CHB + (ln&3)*256 + slot);
      short8 aB = *(const short8*)(Ab + (rowB>>2)*CHB + (ln&3)*256 + slot);
#pragma unroll
      for (int ct = 0; ct < 4; ++ct) {
        short8 bb = *(const short8*)&Bs[(cg*64 + ct*16 + ln)*132 + ks*32 + qd*8];
        acc0[ct] = __builtin_amdgcn_mfma_f32_16x16x32_bf16(aA, bb, acc0[ct], 0,0,0);
        acc1[ct] = __builtin_amdgcn_mfma_f32_16x16x32_bf16(aB, bb, acc1[ct], 0,0,0);
      }
    }

#pragma unroll
    for (int ks = 0; ks < 2; ++ks) {
      short8 ohAu, ohAv, ohBu, ohBv;
#pragma unroll
      for (int j = 0; j < 8; ++j) {
        const int kk = ks*32 + qd*8 + j;
        ohAu[j] = (sa == kk) ? (short)0x3F80 : (short)0;
        ohAv[j] = (da == kk) ? (short)0x3F80 : (short)0;
        ohBu[j] = (sb == kk) ? (short)0x3F80 : (short)0;
        ohBv[j] = (db == kk) ? (short)0x3F80 : (short)0;
      }
#pragma unroll
      for (int ct = 0; ct < 4; ++ct) {
        acc0[ct] = __builtin_amdgcn_mfma_f32_16x16x32_bf16(ohAu, Bu[ks][ct], acc0[ct], 0,0,0);
        acc0[ct] = __builtin_amdgcn_mfma_f32_16x16x32_bf16(ohAv, Bv[ks][ct], acc0[ct], 0,0,0);
        acc1[ct] = __builtin_amdgcn_mfma_f32_16x16x32_bf16(ohBu, Bu[ks][ct], acc1[ct], 0,0,0);
        acc1[ct] = __builtin_amdgcn_mfma_f32_16x16x32_bf16(ohBv, Bv[ks][ct], acc1[ct], 0,0,0);
      }
    }

    float vreg[2][4][4];
#pragma unroll
    for (int mt = 0; mt < 2; ++mt) {
      const f32x4* acc = mt ? acc1 : acc0;
#pragma unroll
      for (int reg = 0; reg < 4; ++reg) {
        int lrow = rh*32 + mt*16 + qd*4 + reg;
        float fp = 0.f;
#pragma unroll
        for (int ct = 0; ct < 4; ++ct) {
          int col = cg*64 + ct*16 + ln;
          int colg = col >> 3;
          float res = s2f(*(const short*)(Ab + (lrow>>2)*CHB + (lrow&3)*256
                         + ((colg ^ ((lrow&3)<<2)) << 4) + (col&7)*2));
          float val = fmaxf(acc[ct][reg] + bias4[ct], 0.f) + res;
          if constexpr (MODE == 1) vreg[mt][reg][ct] = val;
          else fp = fmaf(val, wf4[ct], fp);
        }
        if constexpr (MODE == 2) {
          fp += __shfl_xor(fp, 1, 64);
          fp += __shfl_xor(fp, 2, 64);
          fp += __shfl_xor(fp, 4, 64);
          fp += __shfl_xor(fp, 8, 64);
          if (ln == 0) atomicAdd(&fout[e0 + lrow], fp);
        }
      }
    }

    if constexpr (MODE == 1) {
      __builtin_amdgcn_s_waitcnt(WCNT_LGKM0_ONLY);
      __builtin_amdgcn_s_barrier();
      short* res = (short*)Abuf[nb];
#pragma unroll
      for (int mt = 0; mt < 2; ++mt)
#pragma unroll
        for (int reg = 0; reg < 4; ++reg) {
          int lrow = rh*32 + mt*16 + qd*4 + reg;
#pragma unroll
          for (int ct = 0; ct < 4; ++ct)
            res[lrow*136 + cg*64 + ct*16 + ln] = f2s(vreg[mt][reg][ct]);
        }
      __builtin_amdgcn_s_waitcnt(WCNT_LGKM0_ONLY);
      __builtin_amdgcn_s_barrier();
#pragma unroll
      for (int i = 0; i < 4; ++i) {
        int g = i * 256 + tid;
        int row = g >> 4, ch = g & 15;
        *(uint4*)((short*)m + (size_t)(e0 + row)*128 + ch*8) =
            *(const uint4*)((const char*)Abuf[nb] + row*272 + ch*16);
      }
      __builtin_amdgcn_s_waitcnt(WCNT_LGKM0_ONLY);
      __builtin_amdgcn_s_barrier();
    } else {
      __builtin_amdgcn_s_waitcnt(WCNT_LGKM0_ONLY);
      __builtin_amdgcn_s_barrier();
    }
  }
}

// ===== fused msg+segsum v11b: R6's v11 with ONE fix — dn (dist prefetch)
// issued BEFORE the Mb DMAs in the loop, so its consume-wait next step is
// vmcnt(2) (DMAs stay in flight) instead of vmcnt(0) (early drain).
// Wait constants unchanged: new ops at wait = 8 ta/tb + 1 dn + 2 DMA = 11.
__global__ __launch_bounds__(256, 3) void k_msgagg(
    const __hip_bfloat16* __restrict__ m, const float* __restrict__ dist,
    const __hip_bfloat16* __restrict__ WmT, const float* __restrict__ bm,
    const float* __restrict__ Tg, const int* __restrict__ dst,
    __hip_bfloat16* __restrict__ aggP) {
  __shared__ __align__(16) char gateraw[32 * 140 * 4];  // 17.9 KB gate / epi tile
  __shared__ __align__(16) char Mb[2][8 * CHB];         // 16.6 KB (32 rows dbuf)
  __shared__ short Pt[128 * 40];                        // 10.0 KB  P^T, swz
  __shared__ int dstS[640];                             //  2.5 KB
  float* gate = (float*)gateraw;                        // [32][140]
  const int tid = threadIdx.x;
  const int c  = blockIdx.x >> 1, pq = blockIdx.x & 1;
  const int w = tid >> 6, lane = tid & 63, ln = lane & 15, qd = lane >> 4;
  const int ei = tid >> 3, li = tid & 7;             // gate producer: 32 edges x 16 cols
  const int e_loc = lane >> 4;
  const int sgc = (lane & 15) ^ (e_loc << 2);        // pre-swizzled source col-group
  const int sw8 = (ln & 3) << 3;                     // Pt k-XOR swizzle

  const int ebase = c * 1280 + pq * 640;

  float bias2[2];
#pragma unroll
  for (int ct = 0; ct < 2; ++ct) bias2[ct] = bm[w*32 + ct*16 + ln];

  // loop-invariant B fragments: wave owns cols [w*32, w*32+32)
  short8 Bf[2][4];
#pragma unroll
  for (int ct = 0; ct < 2; ++ct) {
    const short* bp = (const short*)WmT + (size_t)(w*32 + ct*16 + ln)*128 + qd*8;
#pragma unroll
    for (int ks = 0; ks < 4; ++ks) Bf[ct][ks] = *(const short8*)(bp + ks*32);
  }

  // ---- stage dst (640 edges) ----
  for (int i = tid; i < 640; i += 256) dstS[i] = dst[ebase + i] & 63;

  // ---- prologue: Tg(0) + dn + Mb[0] DMA + gate(0) ----
  float4 ta[4], tb[4]; float frc, msk;
  {
    float d0 = dist[ebase + ei];
    msk = (d0 < CUT_F) ? 1.f : 0.f;
    float x = fminf(d0, CUT_F) * ((float)(DQ - 1) / CUT_F);
    int i0 = (int)x; if (i0 > DQ-2) i0 = DQ-2;
    frc = x - (float)i0;
    const float* tp = Tg + (size_t)i0*128 + li*16;
#pragma unroll
    for (int j = 0; j < 4; ++j) {
      ta[j] = *(const float4*)(tp + j*4);
      tb[j] = *(const float4*)(tp + 128 + j*4);
    }
  }
  float dn = dist[ebase + 32 + ei];
#pragma unroll
  for (int t = 0; t < 2; ++t) {
    int chunk = w*2 + t;
    const short* gp = (const short*)m + (size_t)(ebase + chunk*4 + e_loc)*128 + sgc*8;
    DMA16(gp, Mb[0] + chunk*CHB);
  }
#pragma unroll
  for (int j = 0; j < 4; ++j) {
    float4 g;
    g.x = msk * fmaf(frc, tb[j].x - ta[j].x, ta[j].x);
    g.y = msk * fmaf(frc, tb[j].y - ta[j].y, ta[j].y);
    g.z = msk * fmaf(frc, tb[j].z - ta[j].z, ta[j].z);
    g.w = msk * fmaf(frc, tb[j].w - ta[j].w, ta[j].w);
    *(float4*)&gate[ei*140 + li*16 + j*4] = g;
  }
  __builtin_amdgcn_s_waitcnt(WCNT_LGKM0_ONLY);
  __builtin_amdgcn_s_barrier();

  // register-resident aggregate: rows rt*16+qd*4+reg, cols w*32+ct*16+ln
  f32x4 accA[4][2];
#pragma unroll
  for (int rt = 0; rt < 4; ++rt)
#pragma unroll
    for (int ct = 0; ct < 2; ++ct) accA[rt][ct] = (f32x4){0,0,0,0};

  for (int s = 0; s < 20; ++s) {
    const int e0 = ebase + s*32;

    if (s < 19) {
      msk = (dn < CUT_F) ? 1.f : 0.f;
      float x = fminf(dn, CUT_F) * ((float)(DQ - 1) / CUT_F);
      int i0 = (int)x; if (i0 > DQ-2) i0 = DQ-2;
      frc = x - (float)i0;
      const float* tp = Tg + (size_t)i0*128 + li*16;
#pragma unroll
      for (int j = 0; j < 4; ++j) {
        ta[j] = *(const float4*)(tp + j*4);
        tb[j] = *(const float4*)(tp + 128 + j*4);
      }
      if (s < 18)
        dn = dist[e0 + 64 + ei];          // issued BEFORE the DMAs (ledger fix)
#pragma unroll
      for (int t = 0; t < 2; ++t) {
        int chunk = w*2 + t;
        const short* gp = (const short*)m + (size_t)(e0 + 32 + chunk*4 + e_loc)*128 + sgc*8;
        DMA16(gp, Mb[(s+1) & 1] + chunk*CHB);
      }
      if (s < 18) {
        __builtin_amdgcn_s_waitcnt(WCNT_VM11_LGKM0);  // keep {Tg x8, dn, DMA x2}
      } else {
        __builtin_amdgcn_s_waitcnt(WCNT_VM10_LGKM0);  // keep {Tg x8, DMA x2}
      }
    } else {
      __builtin_amdgcn_s_waitcnt(WCNT_VM0_LGKM0);
    }
    __builtin_amdgcn_s_barrier();   // Mb[s] complete, gate(s) visible

    // ---- msg = relu(m @ Wmsg + b): A from Mb (swizzled), B in regs ----
    const char* Ms = Mb[s & 1];
    short8 am[2][4];
#pragma unroll
    for (int et = 0; et < 2; ++et) {
      int r = et*16 + ln;
      const char* rp = Ms + (r>>2)*CHB + (r&3)*256;
      const int sx = (r & 3) << 2;
#pragma unroll
      for (int ks = 0; ks < 4; ++ks)
        am[et][ks] = *(const short8*)(rp + (((ks*4 + qd) ^ sx) << 4));
    }

    f32x4 acc[2][2];
#pragma unroll
    for (int et = 0; et < 2; ++et)
#pragma unroll
      for (int ct = 0; ct < 2; ++ct) acc[et][ct] = (f32x4){0,0,0,0};
#pragma unroll
    for (int ks = 0; ks < 4; ++ks)
#pragma unroll
      for (int et = 0; et < 2; ++et)
#pragma unroll
        for (int ct = 0; ct < 2; ++ct)
          acc[et][ct] = __builtin_amdgcn_mfma_f32_16x16x32_bf16(
              am[et][ks], Bf[ct][ks], acc[et][ct], 0,0,0);

    // ---- P = relu(msg+bias)*gate -> Pt[col][k] (bf16, pair-packed) ----
#pragma unroll
    for (int et = 0; et < 2; ++et)
#pragma unroll
      for (int ct = 0; ct < 2; ++ct) {
        const int col = w*32 + ct*16 + ln;
        float p[4];
#pragma unroll
        for (int reg = 0; reg < 4; ++reg) {
          const int erow = et*16 + qd*4 + reg;
          p[reg] = fmaxf(acc[et][ct][reg] + bias2[ct], 0.f) * gate[erow*140 + col];
        }
        unsigned u01 = (unsigned)(unsigned short)f2s(p[0]) |
                       ((unsigned)(unsigned short)f2s(p[1]) << 16);
        unsigned u23 = (unsigned)(unsigned short)f2s(p[2]) |
                       ((unsigned)(unsigned short)f2s(p[3]) << 16);
        const int a0 = col*40 + ((et*16 + qd*4) ^ sw8);
        *(unsigned*)&Pt[a0]     = u01;
        *(unsigned*)&Pt[a0 + 2] = u23;
      }
    __builtin_amdgcn_s_waitcnt(WCNT_LGKM0_ONLY);
    __builtin_amdgcn_s_barrier();   // Pt visible; gate(s) fully consumed

    // ---- segsum: accA += onehot(dst) @ P  (one K=32 MFMA pair per rt) ----
    int dvj[8];
#pragma unroll
    for (int j = 0; j < 8; ++j) dvj[j] = dstS[s*32 + qd*8 + j];
    short8 pb0 = *(const short8*)&Pt[(w*32 + 0*16 + ln)*40 + ((qd*8) ^ sw8)];
    short8 pb1 = *(const short8*)&Pt[(w*32 + 1*16 + ln)*40 + ((qd*8) ^ sw8)];
#pragma unroll
    for (int rt = 0; rt < 4; ++rt) {
      short8 oh;
#pragma unroll
      for (int j = 0; j < 8; ++j)
        oh[j] = (dvj[j] == rt*16 + ln) ? (short)0x3F80 : (short)0;
      accA[rt][0] = __builtin_amdgcn_mfma_f32_16x16x32_bf16(oh, pb0, accA[rt][0], 0,0,0);
      accA[rt][1] = __builtin_amdgcn_mfma_f32_16x16x32_bf16(oh, pb1, accA[rt][1], 0,0,0);
    }

    // ---- gate(s+1) write (region disjoint from Pt; top barrier protects) ----
    if (s < 19) {
#pragma unroll
      for (int j = 0; j < 4; ++j) {
        float4 g;
        g.x = msk * fmaf(frc, tb[j].x - ta[j].x, ta[j].x);
        g.y = msk * fmaf(frc, tb[j].y - ta[j].y, ta[j].y);
        g.z = msk * fmaf(frc, tb[j].z - ta[j].z, ta[j].z);
        g.w = msk * fmaf(frc, tb[j].w - ta[j].w, ta[j].w);
        *(float4*)&gate[ei*140 + li*16 + j*4] = g;
      }
    }
  }

  // ---- epilogue: accA -> LDS transpose (reuse gate mem) -> full-line stores.
  short* tbuf = (short*)gateraw;   // [64][140]
#pragma unroll
  for (int rt = 0; rt < 4; ++rt)
#pragma unroll
    for (int ct = 0; ct < 2; ++ct) {
      const int col = w*32 + ct*16 + ln;
#pragma unroll
      for (int reg = 0; reg < 4; ++reg)
        tbuf[(rt*16 + qd*4 + reg)*140 + col] = f2s(accA[rt][ct][reg]);
    }
  __builtin_amdgcn_s_waitcnt(WCNT_LGKM0_ONLY);
  __builtin_amdgcn_s_barrier();
  {
    __hip_bfloat16* outp = aggP + ((size_t)pq * NATOMS + c * 64) * HID;
    const int r = tid >> 2, cq = tid & 3;
#pragma unroll
    for (int hh = 0; hh < 4; ++hh) {
      short8 o = *(const short8*)&tbuf[r*140 + cq*32 + hh*8];
      *(uint4*)((short*)outp + (size_t)r*HID + cq*32 + hh*8) = *(uint4*)&o;
    }
  }
}

// ============ FUSED fc+uv: h += relu(sum(slices)@Wa + ba); then
// u = h@Wu, v = h@Wv via LDS C->A layout round-trip. 64 rows/block.
__global__ __launch_bounds__(256) void k_fcuv(
    const __hip_bfloat16* __restrict__ slices,
    const __hip_bfloat16* __restrict__ WTa, const float* __restrict__ ba,
    float* __restrict__ h, __hip_bfloat16* __restrict__ h_bf,
    const __hip_bfloat16* __restrict__ WTu, const __hip_bfloat16* __restrict__ WTv,
    __hip_bfloat16* __restrict__ uo, __hip_bfloat16* __restrict__ vo) {
  __shared__ short ht[64 * 136];   // 17.4 KB fresh-h tile (row pitch 136)
  const int tid = threadIdx.x;
  const int w = tid >> 6, lane = tid & 63, ln = lane & 15, qd = lane >> 4;
  const int row0w = blockIdx.x * 64 + w * 16;
  const int arow = row0w + ln;

  // ---- phase 1: h update (slice sum -> MFMA -> residual) ----
  short8 af[4];
#pragma unroll
  for (int ks = 0; ks < 4; ++ks) {
    float s[8] = {0,0,0,0,0,0,0,0};
#pragma unroll
    for (int p = 0; p < NPART; ++p) {
      short8 v = *(const short8*)((const short*)slices +
                   (size_t)p*NATOMS*128 + (size_t)arow*128 + qd*8 + ks*32);
#pragma unroll
      for (int u = 0; u < 8; ++u) s[u] += s2f(v[u]);
    }
    af[ks] = (short8){f2s(s[0]),f2s(s[1]),f2s(s[2]),f2s(s[3]),
                      f2s(s[4]),f2s(s[5]),f2s(s[6]),f2s(s[7])};
  }

  const short* Wb = (const short*)WTa + ln*128 + qd*8;
  f32x4 acc[8];
#pragma unroll
  for (int ct = 0; ct < 8; ++ct) acc[ct] = (f32x4){0,0,0,0};
#pragma unroll
  for (int ct = 0; ct < 8; ++ct)
#pragma unroll
    for (int ks = 0; ks < 4; ++ks)
      acc[ct] = __builtin_amdgcn_mfma_f32_16x16x32_bf16(af[ks],
                  *(const short8*)(Wb + ct*16*128 + ks*32), acc[ct], 0,0,0);

#pragma unroll
  for (int ct = 0; ct < 8; ++ct) {
    int col = ct*16 + ln;
    float bias = ba[col];
#pragma unroll
    for (int reg = 0; reg < 4; ++reg) {
      int lrow = w*16 + qd*4 + reg;          // row within block's 64
      size_t o = (size_t)(blockIdx.x*64 + lrow)*128 + col;
      float v = fmaxf(acc[ct][reg] + bias, 0.f) + h[o];
      h[o] = v;
      short hb = f2s(v);
      h_bf[o] = *(__hip_bfloat16*)&hb;
      ht[lrow*136 + col] = hb;
    }
  }
  __syncthreads();

  // ---- phase 2: dual projection from LDS tile ----
  short8 ah[4];
  const short* ph = &ht[(w*16 + ln)*136 + qd*8];
#pragma unroll
  for (int ks = 0; ks < 4; ++ks) ah[ks] = *(const short8*)(ph + ks*32);

  f32x4 a1[8], a2[8];
#pragma unroll
  for (int ct = 0; ct < 8; ++ct) { a1[ct] = (f32x4){0,0,0,0}; a2[ct] = (f32x4){0,0,0,0}; }
#pragma unroll
  for (int ct = 0; ct < 8; ++ct) {
    const short* b1 = (const short*)WTu + (ct*16 + ln)*128 + qd*8;
    const short* b2 = (const short*)WTv + (ct*16 + ln)*128 + qd*8;
#pragma unroll
    for (int ks = 0; ks < 4; ++ks) {
      a1[ct] = __builtin_amdgcn_mfma_f32_16x16x32_bf16(ah[ks], *(const short8*)(b1 + ks*32), a1[ct], 0,0,0);
      a2[ct] = __builtin_amdgcn_mfma_f32_16x16x32_bf16(ah[ks], *(const short8*)(b2 + ks*32), a2[ct], 0,0,0);
    }
  }
#pragma unroll
  for (int ct = 0; ct < 8; ++ct) {
    int col = ct*16 + ln;
#pragma unroll
    for (int reg = 0; reg < 4; ++reg) {
      size_t o = (size_t)(row0w + qd*4 + reg)*128 + col;
      uo[o] = f2bf(a1[ct][reg]);
      vo[o] = f2bf(a2[ct][reg]);
    }
  }
}

// ============ FUSED head: a1 = relu(h@W1+b1); a2 = relu(a1@W2+b2);
// out = a2@W3 + b3  (fc3 reduced in-wave). 64 rows/block.
__global__ __launch_bounds__(256) void k_head(
    const __hip_bfloat16* __restrict__ h_bf,
    const __hip_bfloat16* __restrict__ WT1, const float* __restrict__ b1,
    const __hip_bfloat16* __restrict__ WT2, const float* __restrict__ b2,
    const float* __restrict__ W3, const float* __restrict__ b3,
    float* __restrict__ out) {
  __shared__ short t1[64 * 136];   // 17.4 KB a1 tile
  const int tid = threadIdx.x;
  const int w = tid >> 6, lane = tid & 63, ln = lane & 15, qd = lane >> 4;
  const int row0w = blockIdx.x * 64 + w * 16;
  const int arow = row0w + ln;

  // ---- fc1 ----
  short8 af[4];
  const short* pa = (const short*)h_bf + (size_t)arow*128 + qd*8;
#pragma unroll
  for (int ks = 0; ks < 4; ++ks) af[ks] = *(const short8*)(pa + ks*32);

  f32x4 acc[8];
#pragma unroll
  for (int ct = 0; ct < 8; ++ct) acc[ct] = (f32x4){0,0,0,0};
#pragma unroll
  for (int ct = 0; ct < 8; ++ct) {
    const short* bb = (const short*)WT1 + (ct*16 + ln)*128 + qd*8;
#pragma unroll
    for (int ks = 0; ks < 4; ++ks)
      acc[ct] = __builtin_amdgcn_mfma_f32_16x16x32_bf16(af[ks],
                  *(const short8*)(bb + ks*32), acc[ct], 0,0,0);
  }
#pragma unroll
  for (int ct = 0; ct < 8; ++ct) {
    int col = ct*16 + ln;
    float bias = b1[col];
#pragma unroll
    for (int reg = 0; reg < 4; ++reg) {
      int lrow = w*16 + qd*4 + reg;
      t1[lrow*136 + col] = f2s(fmaxf(acc[ct][reg] + bias, 0.f));
    }
  }
  __syncthreads();

  // ---- fc2 ----
  short8 a1f[4];
  const short* p1 = &t1[(w*16 + ln)*136 + qd*8];
#pragma unroll
  for (int ks = 0; ks < 4; ++ks) a1f[ks] = *(const short8*)(p1 + ks*32);

  f32x4 acc2[8];
#pragma unroll
  for (int ct = 0; ct < 8; ++ct) acc2[ct] = (f32x4){0,0,0,0};
#pragma unroll
  for (int ct = 0; ct < 8; ++ct) {
    const short* bb = (const short*)WT2 + (ct*16 + ln)*128 + qd*8;
#pragma unroll
    for (int ks = 0; ks < 4; ++ks)
      acc2[ct] = __builtin_amdgcn_mfma_f32_16x16x32_bf16(a1f[ks],
                   *(const short8*)(bb + ks*32), acc2[ct], 0,0,0);
  }

  // ---- fc3 (in-register): per (reg): p_j = sum_ct a2 * W3[col][j] ----
  float w3a[8], w3b[8];
#pragma unroll
  for (int ct = 0; ct < 8; ++ct) {
    int col = ct*16 + ln;
    w3a[ct] = W3[col*2+0];
    w3b[ct] = W3[col*2+1];
  }
#pragma unroll
  for (int reg = 0; reg < 4; ++reg) {
    float p0 = 0.f, p1v = 0.f;
#pragma unroll
    for (int ct = 0; ct < 8; ++ct) {
      float a2v = fmaxf(acc2[ct][reg] + b2[ct*16 + ln], 0.f);
      p0  = fmaf(a2v, w3a[ct], p0);
      p1v = fmaf(a2v, w3b[ct], p1v);
    }
    p0  += __shfl_xor(p0, 1, 64);  p1v += __shfl_xor(p1v, 1, 64);
    p0  += __shfl_xor(p0, 2, 64);  p1v += __shfl_xor(p1v, 2, 64);
    p0  += __shfl_xor(p0, 4, 64);  p1v += __shfl_xor(p1v, 4, 64);
    p0  += __shfl_xor(p0, 8, 64);  p1v += __shfl_xor(p1v, 8, 64);
    if (ln == 0) {
      int row = row0w + qd*4 + reg;
      out[row*2+0] = p0 + b3[0];
      out[row*2+1] = p1v + b3[1];
    }
  }
}

// ----------------------------------- pred_cart = segsum(f*unit) per crystal
__global__ void k_pcart(const float* __restrict__ f, const float* __restrict__ unit,
                        const int* __restrict__ dst, float* __restrict__ out) {
  __shared__ float acc[AATOMS * 3];
  int c = blockIdx.x, tid = threadIdx.x;  // 256 threads
  if (tid < AATOMS*3) acc[tid] = 0.f;
  __syncthreads();
  for (int t = tid; t < 1280; t += 256) {
    int e = c*1280 + t;
    int d = dst[e] & 63;
    float fv = f[e];
    atomicAdd(&acc[d*3+0], fv * unit[e*3+0]);
    atomicAdd(&acc[d*3+1], fv * unit[e*3+1]);
    atomicAdd(&acc[d*3+2], fv * unit[e*3+2]);
  }
  __syncthreads();
  if (tid < AATOMS*3) out[c*AATOMS*3 + tid] = acc[tid];
}

extern "C" void kernel_launch(void* const* d_in, const int* in_sizes, int n_in,
                              void* d_out, int out_size, void* d_ws, size_t ws_size,
                              hipStream_t stream) {
  const float* z        = (const float*)d_in[0];
  const float* frac     = (const float*)d_in[1];
  const float* lengths  = (const float*)d_in[2];
  const float* angles   = (const float*)d_in[3];
  const int*   atype    = (const int*)  d_in[4];
  const int*   src      = (const int*)  d_in[5];
  const int*   dst      = (const int*)  d_in[6];
  const float* emb      = (const float*)d_in[7];
  const float* W_in     = (const float*)d_in[8];
  const float* b_in     = (const float*)d_in[9];
  const float* W_edge   = (const float*)d_in[10];
  const float* b_edge   = (const float*)d_in[11];
  const float* Wb_rbf   = (const float*)d_in[12];
  const float* Wb_msg   = (const float*)d_in[13];
  const float* bb_msg   = (const float*)d_in[14];
  const float* Wb_atom  = (const float*)d_in[15];
  const float* bb_atom  = (const float*)d_in[16];
  const float* Wb_upd   = (const float*)d_in[17];
  const float* bb_upd   = (const float*)d_in[18];
  const float* W_force  = (const float*)d_in[19];
  const float* b_force  = (const float*)d_in[20];
  const float* W_fc1    = (const float*)d_in[21];
  const float* b_fc1    = (const float*)d_in[22];
  const float* W_fc2    = (const float*)d_in[23];
  const float* b_fc2    = (const float*)d_in[24];
  const float* W_fc3    = (const float*)d_in[25];
  const float* b_fc3    = (const float*)d_in[26];

  // ---- workspace layout ----
  char* p = (char*)d_ws;
  float* cart = (float*)p;            p += (size_t)NATOMS*3*4;
  float* unit = (float*)p;            p += (size_t)NEDGE*3*4;
  float* dist = (float*)p;            p += (size_t)NEDGE*4;
  float* h    = (float*)p;            p += (size_t)NATOMS*HID*4;
  float* fbuf = (float*)p;            p += (size_t)NEDGE*4;
  float* T    = (float*)p;            p += (size_t)4*DQ*128*4;
  __hip_bfloat16* h_bf = (__hip_bfloat16*)p; p += (size_t)NATOMS*HID*2;
  __hip_bfloat16* u0t  = (__hip_bfloat16*)p; p += (size_t)NATOMS*HID*2;
  __hip_bfloat16* v0t  = (__hip_bfloat16*)p; p += (size_t)NATOMS*HID*2;
  __hip_bfloat16* uut  = (__hip_bfloat16*)p; p += (size_t)NATOMS*HID*2;
  __hip_bfloat16* vvt  = (__hip_bfloat16*)p; p += (size_t)NATOMS*HID*2;
  __hip_bfloat16* aggP = (__hip_bfloat16*)p; p += (size_t)NPART*NATOMS*HID*2;
  __hip_bfloat16* m    = (__hip_bfloat16*)p; p += (size_t)NEDGE*HID*2;
  __hip_bfloat16* WT   = (__hip_bfloat16*)p; p += (size_t)360448*2;

  __hip_bfloat16* WT_in   = WT;
  __hip_bfloat16* WTK     = WT + 49152;          // 19 K=128 blocks
  __hip_bfloat16* WT_u0   = WTK + 0*16384;
  __hip_bfloat16* WT_v0   = WTK + 1*16384;
  __hip_bfloat16* WT_updB = WTK + 2*16384;       // (uu,vv,mm) x 3
  __hip_bfloat16* WT_msg  = WTK + 11*16384;
  __hip_bfloat16* WT_atom = WTK + 14*16384;
  __hip_bfloat16* WT_fc1  = WTK + 17*16384;
  __hip_bfloat16* WT_fc2  = WTK + 18*16384;

  float* out_cart = (float*)d_out;
  float* out_at   = out_cart + NATOMS*3;

  k_wcast<<<1408, 256, 0, stream>>>(W_in, W_edge, Wb_upd, Wb_msg, Wb_atom,
                                    W_fc1, W_fc2, WT);
  k_tab<<<DQ, 128, 0, stream>>>(W_edge, Wb_rbf, T);
  k_cart<<<NATOMS/256, 256, 0, stream>>>(frac, lengths, angles, cart);
  k_edge<<<NEDGE/256, 256, 0, stream>>>(cart, src, dst, unit, dist, b_force, fbuf);
  k_hm<<<NATOMS/64, 256, 0, stream>>>(atype, z, emb, WT_in, b_in, h, h_bf);
  k_uv2<<<NATOMS/64, 256, 0, stream>>>(h_bf, WT_u0, WT_v0, u0t, v0t);
  k_minit<<<NEDGE/64, 256, 0, stream>>>(src, dst, dist, u0t, v0t, T, b_edge, m);

  for (int i = 0; i < NBLK; ++i) {
    k_msgagg<<<NCRYST*NPART, 256, 0, stream>>>(m, dist, WT_msg + i*16384,
                                               bb_msg + i*HID, T + (size_t)(1+i)*DQ*128,
                                               dst, aggP);
    k_fcuv<<<NATOMS/64, 256, 0, stream>>>(aggP, WT_atom + i*16384, bb_atom + i*HID,
                                          h, h_bf,
                                          WT_updB + (3*i+0)*16384,
                                          WT_updB + (3*i+1)*16384, uut, vvt);
    if (i < NBLK-1) {
      k_eup<1><<<NCRYST*2, 256, 0, stream>>>(src, dst, m, uut, vvt,
                                             WT_updB + (3*i+2)*16384, bb_upd + i*HID,
                                             nullptr, nullptr);
    } else {
      k_eup<2><<<NCRYST*2, 256, 0, stream>>>(src, dst, m, uut, vvt,
                                             WT_updB + (3*i+2)*16384, bb_upd + i*HID,
                                             W_force, fbuf);
    }
  }
  k_pcart<<<NCRYST, 256, 0, stream>>>(fbuf, unit, dst, out_cart);
  k_head<<<NATOMS/64, 256, 0, stream>>>(h_bf, WT_fc1, b_fc1, WT_fc2, b_fc2,
                                        W_fc3, b_fc3, out_at);
}

// Round 9
// 598.949 us; speedup vs baseline: 1.2752x; 1.0053x over previous
//
#include <hip/hip_runtime.h>
#include <hip/hip_bf16.h>

#define NCRYST 256
#define AATOMS 64
#define KNBR   20
#define HID    128
#define LAT    256
#define NRBF   128
#define NBLK   3
#define NATOMS (NCRYST * AATOMS)   // 16384
#define NEDGE  (NATOMS * KNBR)     // 327680
#define NPART  2                   // agg partial slices per crystal
#define DQ     4096                // dist-table knots over [0, CUT]
#define PI_F   3.14159265358979323846f
#define CUT_F  6.0f
#define CHB    1040                // LDS A chunk stride: 1024 B payload + 16 B pad

typedef short short8 __attribute__((ext_vector_type(8)));   // 8 bf16 (4 VGPRs)
typedef float f32x4  __attribute__((ext_vector_type(4)));   // MFMA C/D

__device__ __forceinline__ float bf2f(__hip_bfloat16 x) { return __bfloat162float(x); }
__device__ __forceinline__ __hip_bfloat16 f2bf(float x) { return __float2bfloat16(x); }
__device__ __forceinline__ float s2f(short x) {
  return __uint_as_float(((unsigned)(unsigned short)x) << 16);
}
__device__ __forceinline__ short f2s(float x) {
  union { short s; __hip_bfloat16 b; } u; u.b = f2bf(x); return u.s;
}

#define DMA16(gptr, lptr) __builtin_amdgcn_global_load_lds( \
    (const __attribute__((address_space(1))) void*)(gptr),  \
    (__attribute__((address_space(3))) void*)(lptr), 16, 0, 0)

// s_waitcnt immediates: vm = bits[3:0], exp = bits[6:4] (7 = no wait),
// lgkm = bits[11:8] (0xF = no wait), vm-high = bits[15:14].
#define WCNT_VM11_LGKM0 0x007B
#define WCNT_VM10_LGKM0 0x007A
#define WCNT_VM4_LGKM0  0x0074
#define WCNT_VM0_LGKM0  0x0070
#define WCNT_LGKM0_ONLY 0xC07F   // vmcnt=63 (no wait), lgkmcnt(0)

// ---------------------------------------------------------------- cart coords
__global__ void k_cart(const float* __restrict__ frac, const float* __restrict__ lengths,
                       const float* __restrict__ angles, float* __restrict__ cart) {
  int atom = blockIdx.x * blockDim.x + threadIdx.x;
  if (atom >= NATOMS) return;
  int c = atom >> 6;
  float al = angles[c*3+0] * (PI_F/180.f);
  float be = angles[c*3+1] * (PI_F/180.f);
  float ga = angles[c*3+2] * (PI_F/180.f);
  float ca = cosf(al), cb = cosf(be), cg = cosf(ga), sg = sinf(ga);
  float a = lengths[c*3+0], b = lengths[c*3+1], cl = lengths[c*3+2];
  float cx = cl * cb;
  float cy = cl * (ca - cb*cg) / sg;
  float cz = sqrtf(fmaxf(cl*cl - cx*cx - cy*cy, 1e-8f));
  float f0 = frac[atom*3+0], f1 = frac[atom*3+1], f2 = frac[atom*3+2];
  cart[atom*3+0] = f0*a + f1*(b*cg) + f2*cx;
  cart[atom*3+1] = f1*(b*sg) + f2*cy;
  cart[atom*3+2] = f2*cz;
}

// ---------------- edge geometry: unit + dist; also init fbuf[e] = b_force
__global__ void k_edge(const float* __restrict__ cart, const int* __restrict__ src,
                       const int* __restrict__ dst, float* __restrict__ unit,
                       float* __restrict__ dist, const float* __restrict__ b_force,
                       float* __restrict__ fbuf) {
  int e = blockIdx.x * blockDim.x + threadIdx.x;
  if (e >= NEDGE) return;
  int s = src[e], d = dst[e];
  float dx = cart[d*3+0] - cart[s*3+0];
  float dy = cart[d*3+1] - cart[s*3+1];
  float dz = cart[d*3+2] - cart[s*3+2];
  float dd = sqrtf(dx*dx + dy*dy + dz*dz + 1e-12f);
  float inv = 1.f / dd;
  dist[e] = dd;
  unit[e*3+0] = dx*inv; unit[e*3+1] = dy*inv; unit[e*3+2] = dz*inv;
  fbuf[e] = b_force[0];
}

// ---------------- dist tables: T[0]=rbf@W_edge[256:384], T[1+i]=rbf@Wb_rbf[i]
__global__ __launch_bounds__(128) void k_tab(const float* __restrict__ W_edge,
                                             const float* __restrict__ Wb_rbf,
                                             float* __restrict__ T) {
  int q = blockIdx.x, n = threadIdx.x;
  __shared__ float rv[128];
  float d = (float)q * (CUT_F / (float)(DQ - 1));
  float env = 0.5f * (cosf(PI_F * fminf(d * (1.f/CUT_F), 1.f)) + 1.f);
  float t = (d - (float)n * (CUT_F/(NRBF-1))) * ((NRBF-1)/CUT_F);
  rv[n] = expf(-t*t) * env;
  __syncthreads();
  float a0 = 0.f, a1 = 0.f, a2 = 0.f, a3 = 0.f;
  for (int j = 0; j < 128; ++j) {
    float r = rv[j];
    a0 = fmaf(r, W_edge[(256 + j)*128 + n], a0);
    a1 = fmaf(r, Wb_rbf[0*16384 + j*128 + n], a1);
    a2 = fmaf(r, Wb_rbf[1*16384 + j*128 + n], a2);
    a3 = fmaf(r, Wb_rbf[2*16384 + j*128 + n], a3);
  }
  T[(0*DQ + q)*128 + n] = a0;
  T[(1*DQ + q)*128 + n] = a1;
  T[(2*DQ + q)*128 + n] = a2;
  T[(3*DQ + q)*128 + n] = a3;
}

// ----------------- weights -> bf16 n-major K=128 blocks (W_in stays K=384)
__global__ void k_wcast(const float* __restrict__ W_in, const float* __restrict__ W_edge,
                        const float* __restrict__ Wb_upd, const float* __restrict__ Wb_msg,
                        const float* __restrict__ Wb_atom, const float* __restrict__ W_fc1,
                        const float* __restrict__ W_fc2, __hip_bfloat16* __restrict__ WT) {
  int idx = blockIdx.x * 256 + threadIdx.x;
  if (idx >= 360448) return;
  if (idx < 49152) {
    int n = idx / 384, k = idx % 384;
    WT[idx] = f2bf(W_in[k*128 + n]);
    return;
  }
  int t = idx - 49152;
  int b = t >> 14, q = t & 16383;
  int n = q >> 7, k = q & 127;
  const float* S; int krow;
  if (b == 0)       { S = W_edge; krow = k; }
  else if (b == 1)  { S = W_edge; krow = 128 + k; }
  else if (b <= 10) { int i = (b-2)/3, part = (b-2)%3;
                      S = Wb_upd + i*49152; krow = part*128 + k; }
  else if (b <= 13) { S = Wb_msg + (b-11)*16384; krow = k; }
  else if (b <= 16) { S = Wb_atom + (b-14)*16384; krow = k; }
  else if (b == 17) { S = W_fc1; krow = k; }
  else              { S = W_fc2; krow = k; }
  WT[idx] = f2bf(S[krow*128 + n]);
}

// ============ FUSED hm+uv: h = relu([emb[atype]|z]@W_in + b); then
// u0 = h@Wu0, v0 = h@Wv0 from the fresh-h LDS tile (k_fcuv pattern).
__global__ __launch_bounds__(256) void k_hmuv(
    const int* __restrict__ atype, const float* __restrict__ z,
    const float* __restrict__ emb, const __hip_bfloat16* __restrict__ WTin,
    const float* __restrict__ b, float* __restrict__ h,
    __hip_bfloat16* __restrict__ h_bf,
    const __hip_bfloat16* __restrict__ WTu, const __hip_bfloat16* __restrict__ WTv,
    __hip_bfloat16* __restrict__ uo, __hip_bfloat16* __restrict__ vo) {
  __shared__ short ht[64 * 136];   // 17.4 KB fresh-h tile (row pitch 136)
  const int tid = threadIdx.x;
  const int w = tid >> 6, lane = tid & 63, ln = lane & 15, qd = lane >> 4;
  const int row0w = blockIdx.x * 64 + w * 16;
  const int arow = row0w + ln;
  const float* esrc = emb + (size_t)atype[arow] * 128;
  const float* zsrc = z + (size_t)(arow >> 6) * LAT;

  short8 af[12];
#pragma unroll
  for (int ks = 0; ks < 4; ++ks) {
    float4 v0 = *(const float4*)(esrc + ks*32 + qd*8);
    float4 v1 = *(const float4*)(esrc + ks*32 + qd*8 + 4);
    af[ks] = (short8){f2s(v0.x),f2s(v0.y),f2s(v0.z),f2s(v0.w),
                      f2s(v1.x),f2s(v1.y),f2s(v1.z),f2s(v1.w)};
  }
#pragma unroll
  for (int ks = 4; ks < 12; ++ks) {
    float4 v0 = *(const float4*)(zsrc + (ks-4)*32 + qd*8);
    float4 v1 = *(const float4*)(zsrc + (ks-4)*32 + qd*8 + 4);
    af[ks] = (short8){f2s(v0.x),f2s(v0.y),f2s(v0.z),f2s(v0.w),
                      f2s(v1.x),f2s(v1.y),f2s(v1.z),f2s(v1.w)};
  }

  const short* Wb = (const short*)WTin + ln*384 + qd*8;
  f32x4 acc[8];
#pragma unroll
  for (int ct = 0; ct < 8; ++ct) acc[ct] = (f32x4){0,0,0,0};
#pragma unroll
  for (int ks = 0; ks < 12; ++ks)
#pragma unroll
    for (int ct = 0; ct < 8; ++ct)
      acc[ct] = __builtin_amdgcn_mfma_f32_16x16x32_bf16(af[ks],
                  *(const short8*)(Wb + ct*16*384 + ks*32), acc[ct], 0,0,0);

#pragma unroll
  for (int ct = 0; ct < 8; ++ct) {
    int col = ct*16 + ln;
    float bias = b[col];
#pragma unroll
    for (int reg = 0; reg < 4; ++reg) {
      int lrow = w*16 + qd*4 + reg;
      float v = fmaxf(acc[ct][reg] + bias, 0.f);
      size_t o = (size_t)(row0w + qd*4 + reg)*128 + col;
      h[o] = v;
      short hb = f2s(v);
      h_bf[o] = *(__hip_bfloat16*)&hb;
      ht[lrow*136 + col] = hb;
    }
  }
  __syncthreads();

  // ---- phase 2: dual projection u0/v0 from LDS tile ----
  short8 ah[4];
  const short* ph = &ht[(w*16 + ln)*136 + qd*8];
#pragma unroll
  for (int ks = 0; ks < 4; ++ks) ah[ks] = *(const short8*)(ph + ks*32);

  f32x4 a1[8], a2[8];
#pragma unroll
  for (int ct = 0; ct < 8; ++ct) { a1[ct] = (f32x4){0,0,0,0}; a2[ct] = (f32x4){0,0,0,0}; }
#pragma unroll
  for (int ct = 0; ct < 8; ++ct) {
    const short* b1 = (const short*)WTu + (ct*16 + ln)*128 + qd*8;
    const short* b2 = (const short*)WTv + (ct*16 + ln)*128 + qd*8;
#pragma unroll
    for (int ks = 0; ks < 4; ++ks) {
      a1[ct] = __builtin_amdgcn_mfma_f32_16x16x32_bf16(ah[ks], *(const short8*)(b1 + ks*32), a1[ct], 0,0,0);
      a2[ct] = __builtin_amdgcn_mfma_f32_16x16x32_bf16(ah[ks], *(const short8*)(b2 + ks*32), a2[ct], 0,0,0);
    }
  }
#pragma unroll
  for (int ct = 0; ct < 8; ++ct) {
    int col = ct*16 + ln;
#pragma unroll
    for (int reg = 0; reg < 4; ++reg) {
      size_t o = (size_t)(row0w + qd*4 + reg)*128 + col;
      uo[o] = f2bf(a1[ct][reg]);
      vo[o] = f2bf(a2[ct][reg]);
    }
  }
}

// ============ m init v2: m = relu(u0[src] + v0[dst] + T0(d) + b)
__global__ __launch_bounds__(256) void k_minit(
    const int* __restrict__ src, const int* __restrict__ dst,
    const float* __restrict__ dist,
    const __hip_bfloat16* __restrict__ u0, const __hip_bfloat16* __restrict__ v0,
    const float* __restrict__ T0, const float* __restrict__ b,
    __hip_bfloat16* __restrict__ m) {
  const int t = threadIdx.x;
  const int li = t & 15, ei = t >> 4;
  float bcol[8];
#pragma unroll
  for (int u = 0; u < 8; ++u) bcol[u] = b[li*8 + u];

  int e[4]; float dd[4]; short8 us[4], vs[4];
#pragma unroll
  for (int g = 0; g < 4; ++g) {
    e[g] = blockIdx.x*64 + g*16 + ei;
    dd[g] = dist[e[g]];
    int s = src[e[g]], d = dst[e[g]];
    us[g] = *(const short8*)((const short*)u0 + (size_t)s*128 + li*8);
    vs[g] = *(const short8*)((const short*)v0 + (size_t)d*128 + li*8);
  }
  float t0v[4][8], t1v[4][8]; float fr[4]; bool in[4];
#pragma unroll
  for (int g = 0; g < 4; ++g) {
    in[g] = dd[g] < CUT_F;
    float x = fminf(dd[g], CUT_F) * ((float)(DQ - 1) / CUT_F);
    int i0 = (int)x;
    fr[g] = x - (float)i0;
    const float* tp = T0 + (size_t)i0*128 + li*8;
    *(float4*)&t0v[g][0] = *(const float4*)tp;
    *(float4*)&t0v[g][4] = *(const float4*)(tp + 4);
    *(float4*)&t1v[g][0] = *(const float4*)(tp + 128);
    *(float4*)&t1v[g][4] = *(const float4*)(tp + 132);
  }
#pragma unroll
  for (int g = 0; g < 4; ++g) {
    short8 o;
#pragma unroll
    for (int u = 0; u < 8; ++u) {
      float tv = in[g] ? fmaf(fr[g], t1v[g][u] - t0v[g][u], t0v[g][u]) : 0.f;
      float v = s2f(us[g][u]) + s2f(vs[g][u]) + tv + bcol[u];
      o[u] = f2s(fmaxf(v, 0.f));
    }
    *(uint4*)((short*)m + (size_t)e[g]*128 + li*8) = *(uint4*)&o;
  }
}

// ============ m update v3: block = (crystal, half), 10 tiles of 64 edges.
// One-hot MFMA gathers (R5). NEW: MODE1 writes m DIRECTLY from registers
// (no LDS res round-trip): 2 barriers/tile instead of 4. Partial-line 2B
// stores are L3-absorbed (R4 counters: WRITE_SIZE 10MB vs 84MB m written).
template<int MODE>
__global__ __launch_bounds__(256) void k_eup(
    const int* __restrict__ src, const int* __restrict__ dst,
    __hip_bfloat16* __restrict__ m,
    const __hip_bfloat16* __restrict__ uu, const __hip_bfloat16* __restrict__ vv,
    const __hip_bfloat16* __restrict__ WTmm, const float* __restrict__ b,
    const float* __restrict__ Wf, float* __restrict__ fout) {
  __shared__ short Bs[128 * 132];                     // 33.8 KB
  __shared__ __align__(16) char Abuf[2][17 * CHB];    // 2 x 17.7 KB
  __shared__ short srcS[640], dstS[640];              //  2.5 KB
  const int tid = threadIdx.x;
  const int w = tid >> 6, lane = tid & 63, ln = lane & 15, qd = lane >> 4;
  const int cg = w & 1, rh = w >> 1;
  const int e_loc = lane >> 4;                        // edge within 4-edge chunk
  const int sgc = (lane & 15) ^ (e_loc << 2);         // pre-swizzled source col-group
  const int cry = blockIdx.x >> 1, half = blockIdx.x & 1;
  const int ebase = cry * 1280 + half * 640;
  const int ca = cry * 64;                            // crystal atom base

#pragma unroll
  for (int i = 0; i < 8; ++i) {
    int g = i * 256 + tid;
    int colb = g >> 4, ch = g & 15;
    *(uint4*)&Bs[colb*132 + ch*8] = ((const uint4*)((const short*)WTmm + colb*128))[ch];
  }
  for (int i = tid; i < 640; i += 256) {
    srcS[i] = (short)(src[ebase + i] & 63);
    dstS[i] = (short)(dst[ebase + i] & 63);
  }

  float bias4[4], wf4[4];
#pragma unroll
  for (int ct = 0; ct < 4; ++ct) bias4[ct] = b[cg*64 + ct*16 + ln];
  if constexpr (MODE == 2) {
#pragma unroll
    for (int ct = 0; ct < 4; ++ct) wf4[ct] = Wf[cg*64 + ct*16 + ln];
  }

  // ---- crystal uu/vv gather B-fragments: B[k=atom][col], regs, once/block ----
  short8 Bu[2][4], Bv[2][4];
#pragma unroll
  for (int ks = 0; ks < 2; ++ks)
#pragma unroll
    for (int ct = 0; ct < 4; ++ct) {
      const int col = cg*64 + ct*16 + ln;
#pragma unroll
      for (int j = 0; j < 8; ++j) {
        const size_t ro = (size_t)(ca + ks*32 + qd*8 + j) * 128 + col;
        Bu[ks][ct][j] = ((const short*)uu)[ro];
        Bv[ks][ct][j] = ((const short*)vv)[ro];
      }
    }

#pragma unroll
  for (int t4 = 0; t4 < 4; ++t4) {
    int chunk = w * 4 + t4;
    const short* gp = (const short*)m + (size_t)(ebase + chunk*4 + e_loc)*128 + sgc*8;
    DMA16(gp, Abuf[0] + chunk * CHB);
  }

  for (int t = 0; t < 10; ++t) {
    const int nb = t & 1;
    if (t < 9) {
#pragma unroll
      for (int t4 = 0; t4 < 4; ++t4) {
        int chunk = w * 4 + t4;
        const short* gp = (const short*)m +
            (size_t)(ebase + (t+1)*64 + chunk*4 + e_loc)*128 + sgc*8;
        DMA16(gp, Abuf[nb^1] + chunk * CHB);
      }
      __builtin_amdgcn_s_waitcnt(WCNT_VM4_LGKM0);   // keep next tile's 4 DMAs
    } else {
      __builtin_amdgcn_s_waitcnt(WCNT_VM0_LGKM0);
    }
    __builtin_amdgcn_s_barrier();

    const char* Ab = Abuf[nb];
    const int e0 = ebase + t*64;
    const int l0 = t*64;

    const int rowA = rh*32 + ln, rowB = rowA + 16;
    const int sa = srcS[l0 + rowA], da = dstS[l0 + rowA];
    const int sb = srcS[l0 + rowB], db = dstS[l0 + rowB];

    f32x4 acc0[4], acc1[4];
#pragma unroll
    for (int ct = 0; ct < 4; ++ct) { acc0[ct] = (f32x4){0,0,0,0}; acc1[ct] = (f32x4){0,0,0,0}; }
    const int sx = (ln & 3) << 2;                     // rowA&3 == rowB&3 == ln&3
#pragma unroll
    for (int ks = 0; ks < 4; ++ks) {
      int slot = ((ks*4 + qd) ^ sx) << 4;
      short8 aA = *(const short8*)(Ab + (rowA>>2)*CHB + (ln&3)*256 + slot);
      short8 aB = *(const short8*)(Ab + (rowB>>2)*CHB + (ln&3)*256 + slot);
#pragma unroll
      for (int ct = 0; ct < 4; ++ct) {
        short8 bb = *(const short8*)&Bs[(cg*64 + ct*16 + ln)*132 + ks*32 + qd*8];
        acc0[ct] = __builtin_amdgcn_mfma_f32_16x16x32_bf16(aA, bb, acc0[ct], 0,0,0);
        acc1[ct] = __builtin_amdgcn_mfma_f32_16x16x32_bf16(aB, bb, acc1[ct], 0,0,0);
      }
    }

#pragma unroll
    for (int ks = 0; ks < 2; ++ks) {
      short8 ohAu, ohAv, ohBu, ohBv;
#pragma unroll
      for (int j = 0; j < 8; ++j) {
        const int kk = ks*32 + qd*8 + j;
        ohAu[j] = (sa == kk) ? (short)0x3F80 : (short)0;
        ohAv[j] = (da == kk) ? (short)0x3F80 : (short)0;
        ohBu[j] = (sb == kk) ? (short)0x3F80 : (short)0;
        ohBv[j] = (db == kk) ? (short)0x3F80 : (short)0;
      }
#pragma unroll
      for (int ct = 0; ct < 4; ++ct) {
        acc0[ct] = __builtin_amdgcn_mfma_f32_16x16x32_bf16(ohAu, Bu[ks][ct], acc0[ct], 0,0,0);
        acc0[ct] = __builtin_amdgcn_mfma_f32_16x16x32_bf16(ohAv, Bv[ks][ct], acc0[ct], 0,0,0);
        acc1[ct] = __builtin_amdgcn_mfma_f32_16x16x32_bf16(ohBu, Bu[ks][ct], acc1[ct], 0,0,0);
        acc1[ct] = __builtin_amdgcn_mfma_f32_16x16x32_bf16(ohBv, Bv[ks][ct], acc1[ct], 0,0,0);
      }
    }

#pragma unroll
    for (int mt = 0; mt < 2; ++mt) {
      const f32x4* acc = mt ? acc1 : acc0;
#pragma unroll
      for (int reg = 0; reg < 4; ++reg) {
        int lrow = rh*32 + mt*16 + qd*4 + reg;
        float fp = 0.f;
#pragma unroll
        for (int ct = 0; ct < 4; ++ct) {
          int col = cg*64 + ct*16 + ln;
          int colg = col >> 3;
          float res = s2f(*(const short*)(Ab + (lrow>>2)*CHB + (lrow&3)*256
                         + ((colg ^ ((lrow&3)<<2)) << 4) + (col&7)*2));
          float val = fmaxf(acc[ct][reg] + bias4[ct], 0.f) + res;
          if constexpr (MODE == 1) {
            // direct register->global m write (no LDS round-trip)
            ((short*)m)[(size_t)(e0 + lrow)*128 + col] = f2s(val);
          } else {
            fp = fmaf(val, wf4[ct], fp);
          }
        }
        if constexpr (MODE == 2) {
          fp += __shfl_xor(fp, 1, 64);
          fp += __shfl_xor(fp, 2, 64);
          fp += __shfl_xor(fp, 4, 64);
          fp += __shfl_xor(fp, 8, 64);
          if (ln == 0) atomicAdd(&fout[e0 + lrow], fp);
        }
      }
    }

    // Abuf[nb] is re-targeted by the DMA issued at the top of iteration t+1;
    // all waves must be past their Ab reads (residual/A-frag) before then.
    __builtin_amdgcn_s_waitcnt(WCNT_LGKM0_ONLY);
    __builtin_amdgcn_s_barrier();
  }
}

// ===== fused msg+segsum v11b (R8 best): counted-vmcnt pipeline, one-hot MFMA
// segsum into ACC regs, LDS-transposed vectorized epilogue.
__global__ __launch_bounds__(256, 3) void k_msgagg(
    const __hip_bfloat16* __restrict__ m, const float* __restrict__ dist,
    const __hip_bfloat16* __restrict__ WmT, const float* __restrict__ bm,
    const float* __restrict__ Tg, const int* __restrict__ dst,
    __hip_bfloat16* __restrict__ aggP) {
  __shared__ __align__(16) char gateraw[32 * 140 * 4];  // 17.9 KB gate / epi tile
  __shared__ __align__(16) char Mb[2][8 * CHB];         // 16.6 KB (32 rows dbuf)
  __shared__ short Pt[128 * 40];                        // 10.0 KB  P^T, swz
  __shared__ int dstS[640];                             //  2.5 KB
  float* gate = (float*)gateraw;                        // [32][140]
  const int tid = threadIdx.x;
  const int c  = blockIdx.x >> 1, pq = blockIdx.x & 1;
  const int w = tid >> 6, lane = tid & 63, ln = lane & 15, qd = lane >> 4;
  const int ei = tid >> 3, li = tid & 7;             // gate producer: 32 edges x 16 cols
  const int e_loc = lane >> 4;
  const int sgc = (lane & 15) ^ (e_loc << 2);        // pre-swizzled source col-group
  const int sw8 = (ln & 3) << 3;                     // Pt k-XOR swizzle

  const int ebase = c * 1280 + pq * 640;

  float bias2[2];
#pragma unroll
  for (int ct = 0; ct < 2; ++ct) bias2[ct] = bm[w*32 + ct*16 + ln];

  // loop-invariant B fragments: wave owns cols [w*32, w*32+32)
  short8 Bf[2][4];
#pragma unroll
  for (int ct = 0; ct < 2; ++ct) {
    const short* bp = (const short*)WmT + (size_t)(w*32 + ct*16 + ln)*128 + qd*8;
#pragma unroll
    for (int ks = 0; ks < 4; ++ks) Bf[ct][ks] = *(const short8*)(bp + ks*32);
  }

  // ---- stage dst (640 edges) ----
  for (int i = tid; i < 640; i += 256) dstS[i] = dst[ebase + i] & 63;

  // ---- prologue: Tg(0) + dn + Mb[0] DMA + gate(0) ----
  float4 ta[4], tb[4]; float frc, msk;
  {
    float d0 = dist[ebase + ei];
    msk = (d0 < CUT_F) ? 1.f : 0.f;
    float x = fminf(d0, CUT_F) * ((float)(DQ - 1) / CUT_F);
    int i0 = (int)x; if (i0 > DQ-2) i0 = DQ-2;
    frc = x - (float)i0;
    const float* tp = Tg + (size_t)i0*128 + li*16;
#pragma unroll
    for (int j = 0; j < 4; ++j) {
      ta[j] = *(const float4*)(tp + j*4);
      tb[j] = *(const float4*)(tp + 128 + j*4);
    }
  }
  float dn = dist[ebase + 32 + ei];
#pragma unroll
  for (int t = 0; t < 2; ++t) {
    int chunk = w*2 + t;
    const short* gp = (const short*)m + (size_t)(ebase + chunk*4 + e_loc)*128 + sgc*8;
    DMA16(gp, Mb[0] + chunk*CHB);
  }
#pragma unroll
  for (int j = 0; j < 4; ++j) {
    float4 g;
    g.x = msk * fmaf(frc, tb[j].x - ta[j].x, ta[j].x);
    g.y = msk * fmaf(frc, tb[j].y - ta[j].y, ta[j].y);
    g.z = msk * fmaf(frc, tb[j].z - ta[j].z, ta[j].z);
    g.w = msk * fmaf(frc, tb[j].w - ta[j].w, ta[j].w);
    *(float4*)&gate[ei*140 + li*16 + j*4] = g;
  }
  __builtin_amdgcn_s_waitcnt(WCNT_LGKM0_ONLY);
  __builtin_amdgcn_s_barrier();

  // register-resident aggregate: rows rt*16+qd*4+reg, cols w*32+ct*16+ln
  f32x4 accA[4][2];
#pragma unroll
  for (int rt = 0; rt < 4; ++rt)
#pragma unroll
    for (int ct = 0; ct < 2; ++ct) accA[rt][ct] = (f32x4){0,0,0,0};

  for (int s = 0; s < 20; ++s) {
    const int e0 = ebase + s*32;

    if (s < 19) {
      msk = (dn < CUT_F) ? 1.f : 0.f;
      float x = fminf(dn, CUT_F) * ((float)(DQ - 1) / CUT_F);
      int i0 = (int)x; if (i0 > DQ-2) i0 = DQ-2;
      frc = x - (float)i0;
      const float* tp = Tg + (size_t)i0*128 + li*16;
#pragma unroll
      for (int j = 0; j < 4; ++j) {
        ta[j] = *(const float4*)(tp + j*4);
        tb[j] = *(const float4*)(tp + 128 + j*4);
      }
      if (s < 18)
        dn = dist[e0 + 64 + ei];          // issued BEFORE the DMAs (ledger fix)
#pragma unroll
      for (int t = 0; t < 2; ++t) {
        int chunk = w*2 + t;
        const short* gp = (const short*)m + (size_t)(e0 + 32 + chunk*4 + e_loc)*128 + sgc*8;
        DMA16(gp, Mb[(s+1) & 1] + chunk*CHB);
      }
      if (s < 18) {
        __builtin_amdgcn_s_waitcnt(WCNT_VM11_LGKM0);  // keep {Tg x8, dn, DMA x2}
      } else {
        __builtin_amdgcn_s_waitcnt(WCNT_VM10_LGKM0);  // keep {Tg x8, DMA x2}
      }
    } else {
      __builtin_amdgcn_s_waitcnt(WCNT_VM0_LGKM0);
    }
    __builtin_amdgcn_s_barrier();   // Mb[s] complete, gate(s) visible

    // ---- msg = relu(m @ Wmsg + b): A from Mb (swizzled), B in regs ----
    const char* Ms = Mb[s & 1];
    short8 am[2][4];
#pragma unroll
    for (int et = 0; et < 2; ++et) {
      int r = et*16 + ln;
      const char* rp = Ms + (r>>2)*CHB + (r&3)*256;
      const int sx = (r & 3) << 2;
#pragma unroll
      for (int ks = 0; ks < 4; ++ks)
        am[et][ks] = *(const short8*)(rp + (((ks*4 + qd) ^ sx) << 4));
    }

    f32x4 acc[2][2];
#pragma unroll
    for (int et = 0; et < 2; ++et)
#pragma unroll
      for (int ct = 0; ct < 2; ++ct) acc[et][ct] = (f32x4){0,0,0,0};
#pragma unroll
    for (int ks = 0; ks < 4; ++ks)
#pragma unroll
      for (int et = 0; et < 2; ++et)
#pragma unroll
        for (int ct = 0; ct < 2; ++ct)
          acc[et][ct] = __builtin_amdgcn_mfma_f32_16x16x32_bf16(
              am[et][ks], Bf[ct][ks], acc[et][ct], 0,0,0);

    // ---- P = relu(msg+bias)*gate -> Pt[col][k] (bf16, pair-packed) ----
#pragma unroll
    for (int et = 0; et < 2; ++et)
#pragma unroll
      for (int ct = 0; ct < 2; ++ct) {
        const int col = w*32 + ct*16 + ln;
        float p[4];
#pragma unroll
        for (int reg = 0; reg < 4; ++reg) {
          const int erow = et*16 + qd*4 + reg;
          p[reg] = fmaxf(acc[et][ct][reg] + bias2[ct], 0.f) * gate[erow*140 + col];
        }
        unsigned u01 = (unsigned)(unsigned short)f2s(p[0]) |
                       ((unsigned)(unsigned short)f2s(p[1]) << 16);
        unsigned u23 = (unsigned)(unsigned short)f2s(p[2]) |
                       ((unsigned)(unsigned short)f2s(p[3]) << 16);
        const int a0 = col*40 + ((et*16 + qd*4) ^ sw8);
        *(unsigned*)&Pt[a0]     = u01;
        *(unsigned*)&Pt[a0 + 2] = u23;
      }
    __builtin_amdgcn_s_waitcnt(WCNT_LGKM0_ONLY);
    __builtin_amdgcn_s_barrier();   // Pt visible; gate(s) fully consumed

    // ---- segsum: accA += onehot(dst) @ P  (one K=32 MFMA pair per rt) ----
    int dvj[8];
#pragma unroll
    for (int j = 0; j < 8; ++j) dvj[j] = dstS[s*32 + qd*8 + j];
    short8 pb0 = *(const short8*)&Pt[(w*32 + 0*16 + ln)*40 + ((qd*8) ^ sw8)];
    short8 pb1 = *(const short8*)&Pt[(w*32 + 1*16 + ln)*40 + ((qd*8) ^ sw8)];
#pragma unroll
    for (int rt = 0; rt < 4; ++rt) {
      short8 oh;
#pragma unroll
      for (int j = 0; j < 8; ++j)
        oh[j] = (dvj[j] == rt*16 + ln) ? (short)0x3F80 : (short)0;
      accA[rt][0] = __builtin_amdgcn_mfma_f32_16x16x32_bf16(oh, pb0, accA[rt][0], 0,0,0);
      accA[rt][1] = __builtin_amdgcn_mfma_f32_16x16x32_bf16(oh, pb1, accA[rt][1], 0,0,0);
    }

    // ---- gate(s+1) write (region disjoint from Pt; top barrier protects) ----
    if (s < 19) {
#pragma unroll
      for (int j = 0; j < 4; ++j) {
        float4 g;
        g.x = msk * fmaf(frc, tb[j].x - ta[j].x, ta[j].x);
        g.y = msk * fmaf(frc, tb[j].y - ta[j].y, ta[j].y);
        g.z = msk * fmaf(frc, tb[j].z - ta[j].z, ta[j].z);
        g.w = msk * fmaf(frc, tb[j].w - ta[j].w, ta[j].w);
        *(float4*)&gate[ei*140 + li*16 + j*4] = g;
      }
    }
  }

  // ---- epilogue: accA -> LDS transpose (reuse gate mem) -> full-line stores.
  short* tbuf = (short*)gateraw;   // [64][140]
#pragma unroll
  for (int rt = 0; rt < 4; ++rt)
#pragma unroll
    for (int ct = 0; ct < 2; ++ct) {
      const int col = w*32 + ct*16 + ln;
#pragma unroll
      for (int reg = 0; reg < 4; ++reg)
        tbuf[(rt*16 + qd*4 + reg)*140 + col] = f2s(accA[rt][ct][reg]);
    }
  __builtin_amdgcn_s_waitcnt(WCNT_LGKM0_ONLY);
  __builtin_amdgcn_s_barrier();
  {
    __hip_bfloat16* outp = aggP + ((size_t)pq * NATOMS + c * 64) * HID;
    const int r = tid >> 2, cq = tid & 3;
#pragma unroll
    for (int hh = 0; hh < 4; ++hh) {
      short8 o = *(const short8*)&tbuf[r*140 + cq*32 + hh*8];
      *(uint4*)((short*)outp + (size_t)r*HID + cq*32 + hh*8) = *(uint4*)&o;
    }
  }
}

// ============ FUSED fc+uv: h += relu(sum(slices)@Wa + ba); then
// u = h@Wu, v = h@Wv via LDS C->A layout round-trip. 64 rows/block.
__global__ __launch_bounds__(256) void k_fcuv(
    const __hip_bfloat16* __restrict__ slices,
    const __hip_bfloat16* __restrict__ WTa, const float* __restrict__ ba,
    float* __restrict__ h, __hip_bfloat16* __restrict__ h_bf,
    const __hip_bfloat16* __restrict__ WTu, const __hip_bfloat16* __restrict__ WTv,
    __hip_bfloat16* __restrict__ uo, __hip_bfloat16* __restrict__ vo) {
  __shared__ short ht[64 * 136];   // 17.4 KB fresh-h tile (row pitch 136)
  const int tid = threadIdx.x;
  const int w = tid >> 6, lane = tid & 63, ln = lane & 15, qd = lane >> 4;
  const int row0w = blockIdx.x * 64 + w * 16;
  const int arow = row0w + ln;

  // ---- phase 1: h update (slice sum -> MFMA -> residual) ----
  short8 af[4];
#pragma unroll
  for (int ks = 0; ks < 4; ++ks) {
    float s[8] = {0,0,0,0,0,0,0,0};
#pragma unroll
    for (int p = 0; p < NPART; ++p) {
      short8 v = *(const short8*)((const short*)slices +
                   (size_t)p*NATOMS*128 + (size_t)arow*128 + qd*8 + ks*32);
#pragma unroll
      for (int u = 0; u < 8; ++u) s[u] += s2f(v[u]);
    }
    af[ks] = (short8){f2s(s[0]),f2s(s[1]),f2s(s[2]),f2s(s[3]),
                      f2s(s[4]),f2s(s[5]),f2s(s[6]),f2s(s[7])};
  }

  const short* Wb = (const short*)WTa + ln*128 + qd*8;
  f32x4 acc[8];
#pragma unroll
  for (int ct = 0; ct < 8; ++ct) acc[ct] = (f32x4){0,0,0,0};
#pragma unroll
  for (int ct = 0; ct < 8; ++ct)
#pragma unroll
    for (int ks = 0; ks < 4; ++ks)
      acc[ct] = __builtin_amdgcn_mfma_f32_16x16x32_bf16(af[ks],
                  *(const short8*)(Wb + ct*16*128 + ks*32), acc[ct], 0,0,0);

#pragma unroll
  for (int ct = 0; ct < 8; ++ct) {
    int col = ct*16 + ln;
    float bias = ba[col];
#pragma unroll
    for (int reg = 0; reg < 4; ++reg) {
      int lrow = w*16 + qd*4 + reg;          // row within block's 64
      size_t o = (size_t)(blockIdx.x*64 + lrow)*128 + col;
      float v = fmaxf(acc[ct][reg] + bias, 0.f) + h[o];
      h[o] = v;
      short hb = f2s(v);
      h_bf[o] = *(__hip_bfloat16*)&hb;
      ht[lrow*136 + col] = hb;
    }
  }
  __syncthreads();

  // ---- phase 2: dual projection from LDS tile ----
  short8 ah[4];
  const short* ph = &ht[(w*16 + ln)*136 + qd*8];
#pragma unroll
  for (int ks = 0; ks < 4; ++ks) ah[ks] = *(const short8*)(ph + ks*32);

  f32x4 a1[8], a2[8];
#pragma unroll
  for (int ct = 0; ct < 8; ++ct) { a1[ct] = (f32x4){0,0,0,0}; a2[ct] = (f32x4){0,0,0,0}; }
#pragma unroll
  for (int ct = 0; ct < 8; ++ct) {
    const short* b1 = (const short*)WTu + (ct*16 + ln)*128 + qd*8;
    const short* b2 = (const short*)WTv + (ct*16 + ln)*128 + qd*8;
#pragma unroll
    for (int ks = 0; ks < 4; ++ks) {
      a1[ct] = __builtin_amdgcn_mfma_f32_16x16x32_bf16(ah[ks], *(const short8*)(b1 + ks*32), a1[ct], 0,0,0);
      a2[ct] = __builtin_amdgcn_mfma_f32_16x16x32_bf16(ah[ks], *(const short8*)(b2 + ks*32), a2[ct], 0,0,0);
    }
  }
#pragma unroll
  for (int ct = 0; ct < 8; ++ct) {
    int col = ct*16 + ln;
#pragma unroll
    for (int reg = 0; reg < 4; ++reg) {
      size_t o = (size_t)(row0w + qd*4 + reg)*128 + col;
      uo[o] = f2bf(a1[ct][reg]);
      vo[o] = f2bf(a2[ct][reg]);
    }
  }
}

// ============ FUSED head: a1 = relu(h@W1+b1); a2 = relu(a1@W2+b2);
// out = a2@W3 + b3  (fc3 reduced in-wave). 64 rows/block.
__global__ __launch_bounds__(256) void k_head(
    const __hip_bfloat16* __restrict__ h_bf,
    const __hip_bfloat16* __restrict__ WT1, const float* __restrict__ b1,
    const __hip_bfloat16* __restrict__ WT2, const float* __restrict__ b2,
    const float* __restrict__ W3, const float* __restrict__ b3,
    float* __restrict__ out) {
  __shared__ short t1[64 * 136];   // 17.4 KB a1 tile
  const int tid = threadIdx.x;
  const int w = tid >> 6, lane = tid & 63, ln = lane & 15, qd = lane >> 4;
  const int row0w = blockIdx.x * 64 + w * 16;
  const int arow = row0w + ln;

  // ---- fc1 ----
  short8 af[4];
  const short* pa = (const short*)h_bf + (size_t)arow*128 + qd*8;
#pragma unroll
  for (int ks = 0; ks < 4; ++ks) af[ks] = *(const short8*)(pa + ks*32);

  f32x4 acc[8];
#pragma unroll
  for (int ct = 0; ct < 8; ++ct) acc[ct] = (f32x4){0,0,0,0};
#pragma unroll
  for (int ct = 0; ct < 8; ++ct) {
    const short* bb = (const short*)WT1 + (ct*16 + ln)*128 + qd*8;
#pragma unroll
    for (int ks = 0; ks < 4; ++ks)
      acc[ct] = __builtin_amdgcn_mfma_f32_16x16x32_bf16(af[ks],
                  *(const short8*)(bb + ks*32), acc[ct], 0,0,0);
  }
#pragma unroll
  for (int ct = 0; ct < 8; ++ct) {
    int col = ct*16 + ln;
    float bias = b1[col];
#pragma unroll
    for (int reg = 0; reg < 4; ++reg) {
      int lrow = w*16 + qd*4 + reg;
      t1[lrow*136 + col] = f2s(fmaxf(acc[ct][reg] + bias, 0.f));
    }
  }
  __syncthreads();

  // ---- fc2 ----
  short8 a1f[4];
  const short* p1 = &t1[(w*16 + ln)*136 + qd*8];
#pragma unroll
  for (int ks = 0; ks < 4; ++ks) a1f[ks] = *(const short8*)(p1 + ks*32);

  f32x4 acc2[8];
#pragma unroll
  for (int ct = 0; ct < 8; ++ct) acc2[ct] = (f32x4){0,0,0,0};
#pragma unroll
  for (int ct = 0; ct < 8; ++ct) {
    const short* bb = (const short*)WT2 + (ct*16 + ln)*128 + qd*8;
#pragma unroll
    for (int ks = 0; ks < 4; ++ks)
      acc2[ct] = __builtin_amdgcn_mfma_f32_16x16x32_bf16(a1f[ks],
                   *(const short8*)(bb + ks*32), acc2[ct], 0,0,0);
  }

  // ---- fc3 (in-register): per (reg): p_j = sum_ct a2 * W3[col][j] ----
  float w3a[8], w3b[8];
#pragma unroll
  for (int ct = 0; ct < 8; ++ct) {
    int col = ct*16 + ln;
    w3a[ct] = W3[col*2+0];
    w3b[ct] = W3[col*2+1];
  }
#pragma unroll
  for (int reg = 0; reg < 4; ++reg) {
    float p0 = 0.f, p1v = 0.f;
#pragma unroll
    for (int ct = 0; ct < 8; ++ct) {
      float a2v = fmaxf(acc2[ct][reg] + b2[ct*16 + ln], 0.f);
      p0  = fmaf(a2v, w3a[ct], p0);
      p1v = fmaf(a2v, w3b[ct], p1v);
    }
    p0  += __shfl_xor(p0, 1, 64);  p1v += __shfl_xor(p1v, 1, 64);
    p0  += __shfl_xor(p0, 2, 64);  p1v += __shfl_xor(p1v, 2, 64);
    p0  += __shfl_xor(p0, 4, 64);  p1v += __shfl_xor(p1v, 4, 64);
    p0  += __shfl_xor(p0, 8, 64);  p1v += __shfl_xor(p1v, 8, 64);
    if (ln == 0) {
      int row = row0w + qd*4 + reg;
      out[row*2+0] = p0 + b3[0];
      out[row*2+1] = p1v + b3[1];
    }
  }
}

// ----------------------------------- pred_cart = segsum(f*unit) per crystal
__global__ void k_pcart(const float* __restrict__ f, const float* __restrict__ unit,
                        const int* __restrict__ dst, float* __restrict__ out) {
  __shared__ float acc[AATOMS * 3];
  int c = blockIdx.x, tid = threadIdx.x;  // 256 threads
  if (tid < AATOMS*3) acc[tid] = 0.f;
  __syncthreads();
  for (int t = tid; t < 1280; t += 256) {
    int e = c*1280 + t;
    int d = dst[e] & 63;
    float fv = f[e];
    atomicAdd(&acc[d*3+0], fv * unit[e*3+0]);
    atomicAdd(&acc[d*3+1], fv * unit[e*3+1]);
    atomicAdd(&acc[d*3+2], fv * unit[e*3+2]);
  }
  __syncthreads();
  if (tid < AATOMS*3) out[c*AATOMS*3 + tid] = acc[tid];
}

extern "C" void kernel_launch(void* const* d_in, const int* in_sizes, int n_in,
                              void* d_out, int out_size, void* d_ws, size_t ws_size,
                              hipStream_t stream) {
  const float* z        = (const float*)d_in[0];
  const float* frac     = (const float*)d_in[1];
  const float* lengths  = (const float*)d_in[2];
  const float* angles   = (const float*)d_in[3];
  const int*   atype    = (const int*)  d_in[4];
  const int*   src      = (const int*)  d_in[5];
  const int*   dst      = (const int*)  d_in[6];
  const float* emb      = (const float*)d_in[7];
  const float* W_in     = (const float*)d_in[8];
  const float* b_in     = (const float*)d_in[9];
  const float* W_edge   = (const float*)d_in[10];
  const float* b_edge   = (const float*)d_in[11];
  const float* Wb_rbf   = (const float*)d_in[12];
  const float* Wb_msg   = (const float*)d_in[13];
  const float* bb_msg   = (const float*)d_in[14];
  const float* Wb_atom  = (const float*)d_in[15];
  const float* bb_atom  = (const float*)d_in[16];
  const float* Wb_upd   = (const float*)d_in[17];
  const float* bb_upd   = (const float*)d_in[18];
  const float* W_force  = (const float*)d_in[19];
  const float* b_force  = (const float*)d_in[20];
  const float* W_fc1    = (const float*)d_in[21];
  const float* b_fc1    = (const float*)d_in[22];
  const float* W_fc2    = (const float*)d_in[23];
  const float* b_fc2    = (const float*)d_in[24];
  const float* W_fc3    = (const float*)d_in[25];
  const float* b_fc3    = (const float*)d_in[26];

  // ---- workspace layout ----
  char* p = (char*)d_ws;
  float* cart = (float*)p;            p += (size_t)NATOMS*3*4;
  float* unit = (float*)p;            p += (size_t)NEDGE*3*4;
  float* dist = (float*)p;            p += (size_t)NEDGE*4;
  float* h    = (float*)p;            p += (size_t)NATOMS*HID*4;
  float* fbuf = (float*)p;            p += (size_t)NEDGE*4;
  float* T    = (float*)p;            p += (size_t)4*DQ*128*4;
  __hip_bfloat16* h_bf = (__hip_bfloat16*)p; p += (size_t)NATOMS*HID*2;
  __hip_bfloat16* u0t  = (__hip_bfloat16*)p; p += (size_t)NATOMS*HID*2;
  __hip_bfloat16* v0t  = (__hip_bfloat16*)p; p += (size_t)NATOMS*HID*2;
  __hip_bfloat16* uut  = (__hip_bfloat16*)p; p += (size_t)NATOMS*HID*2;
  __hip_bfloat16* vvt  = (__hip_bfloat16*)p; p += (size_t)NATOMS*HID*2;
  __hip_bfloat16* aggP = (__hip_bfloat16*)p; p += (size_t)NPART*NATOMS*HID*2;
  __hip_bfloat16* m    = (__hip_bfloat16*)p; p += (size_t)NEDGE*HID*2;
  __hip_bfloat16* WT   = (__hip_bfloat16*)p; p += (size_t)360448*2;

  __hip_bfloat16* WT_in   = WT;
  __hip_bfloat16* WTK     = WT + 49152;          // 19 K=128 blocks
  __hip_bfloat16* WT_u0   = WTK + 0*16384;
  __hip_bfloat16* WT_v0   = WTK + 1*16384;
  __hip_bfloat16* WT_updB = WTK + 2*16384;       // (uu,vv,mm) x 3
  __hip_bfloat16* WT_msg  = WTK + 11*16384;
  __hip_bfloat16* WT_atom = WTK + 14*16384;
  __hip_bfloat16* WT_fc1  = WTK + 17*16384;
  __hip_bfloat16* WT_fc2  = WTK + 18*16384;

  float* out_cart = (float*)d_out;
  float* out_at   = out_cart + NATOMS*3;

  k_wcast<<<1408, 256, 0, stream>>>(W_in, W_edge, Wb_upd, Wb_msg, Wb_atom,
                                    W_fc1, W_fc2, WT);
  k_tab<<<DQ, 128, 0, stream>>>(W_edge, Wb_rbf, T);
  k_cart<<<NATOMS/256, 256, 0, stream>>>(frac, lengths, angles, cart);
  k_edge<<<NEDGE/256, 256, 0, stream>>>(cart, src, dst, unit, dist, b_force, fbuf);
  k_hmuv<<<NATOMS/64, 256, 0, stream>>>(atype, z, emb, WT_in, b_in, h, h_bf,
                                        WT_u0, WT_v0, u0t, v0t);
  k_minit<<<NEDGE/64, 256, 0, stream>>>(src, dst, dist, u0t, v0t, T, b_edge, m);

  for (int i = 0; i < NBLK; ++i) {
    k_msgagg<<<NCRYST*NPART, 256, 0, stream>>>(m, dist, WT_msg + i*16384,
                                               bb_msg + i*HID, T + (size_t)(1+i)*DQ*128,
                                               dst, aggP);
    k_fcuv<<<NATOMS/64, 256, 0, stream>>>(aggP, WT_atom + i*16384, bb_atom + i*HID,
                                          h, h_bf,
                                          WT_updB + (3*i+0)*16384,
                                          WT_updB + (3*i+1)*16384, uut, vvt);
    if (i < NBLK-1) {
      k_eup<1><<<NCRYST*2, 256, 0, stream>>>(src, dst, m, uut, vvt,
                                             WT_updB + (3*i+2)*16384, bb_upd + i*HID,
                                             nullptr, nullptr);
    } else {
      k_eup<2><<<NCRYST*2, 256, 0, stream>>>(src, dst, m, uut, vvt,
                                             WT_updB + (3*i+2)*16384, bb_upd + i*HID,
                                             W_force, fbuf);
    }
  }
  k_pcart<<<NCRYST, 256, 0, stream>>>(fbuf, unit, dst, out_cart);
  k_head<<<NATOMS/64, 256, 0, stream>>>(h_bf, WT_fc1, b_fc1, WT_fc2, b_fc2,
                                        W_fc3, b_fc3, out_at);
}